// Round 1
// baseline (1874.516 us; speedup 1.0000x reference)
//
#include <hip/hip_runtime.h>
#include <math.h>

// ---------------- problem constants ----------------
#define BB 4
#define NN 20000
#define CC 256
#define VV 300
#define SS 1024

// output float offsets (concatenated flat, all read back as float32)
#define O_GRASP   0          // (4,20000)
#define O_OBJ     80000      // (4,20000)
#define O_GXYZ    160000     // (4,1024,3)
#define O_INDS    172288     // (4,1024)
#define O_GFEAT   176384     // (4,256,1024)
#define O_FPG     1224960    // (4,1024)
#define O_VIEW    1229056    // (4,1024,300)
#define O_TVI     2457856    // (4,1024)
#define O_TVS     2461952    // (4,1024)
#define O_VPX     2466048    // (4,1024,3)
#define O_VPR     2478336    // (4,1024,3,3)

// ws float offsets
#define W_GH1T    0          // [256 c][256 o]
#define W_W1T     65536      // [256 c][256 o]
#define W_W2T     131072     // [256 c][320 o-pad] (O=300)
#define W_W3T     212992     // [300 c][320 o-pad] (O=300)
#define W_TMPL    308992     // 300*3
#define W_SGH     309892     // 256
#define W_SC1     310148     // 256
#define W_SC2     310404     // 300
#define W_CNT     310704     // 4 ints (pad to 310720)
#define W_CPK     310720     // 4*20000 float4 (x,y,z,idx-bits)
#define W_INDS    630720     // 4*1024 int
#define W_MASK    634816     // 4*20000 int
#define W_F1      714816     // 4*256*1024
#define W_F2      1763392    // 4*300*1024
#define W_F3      2992192    // 4*300*1024  (end 4220992 floats = 16.9 MB)

__device__ __forceinline__ unsigned int fmono(float f) {
    unsigned int u = __float_as_uint(f);
    return (u & 0x80000000u) ? ~u : (u | 0x80000000u);
}

// ---------------- K0: prep (transposes, bn scales, templates, cnt=0) ----------------
__global__ void k0_prep(const float* __restrict__ w_gh1, const float* __restrict__ w1,
                        const float* __restrict__ w2, const float* __restrict__ w3,
                        const float* __restrict__ gh_g, const float* __restrict__ gh_v,
                        const float* __restrict__ g1, const float* __restrict__ v1,
                        const float* __restrict__ g2, const float* __restrict__ v2,
                        float* __restrict__ ws) {
    int id = blockIdx.x * 256 + threadIdx.x;
    if (id < 65536) {
        int k = id & 255, o = id >> 8;               // id = o*256+k (coalesced read)
        ws[W_GH1T + k * 256 + o] = w_gh1[id];
    } else if (id < 131072) {
        int l = id - 65536; int k = l & 255, o = l >> 8;
        ws[W_W1T + k * 256 + o] = w1[l];
    } else if (id < 207872) {
        int l = id - 131072; int k = l & 255, o = l >> 8;   // o < 300
        ws[W_W2T + k * 320 + o] = w2[l];
    } else if (id < 297872) {
        int l = id - 207872; int k = l % 300, o = l / 300;
        ws[W_W3T + k * 320 + o] = w3[l];
    } else if (id < 298172) {
        int i = id - 297872;
        double phi = (sqrt(5.0) - 1.0) / 2.0;
        double zi = (2.0 * (double)i + 1.0) / 300.0 - 1.0;
        double r2 = 1.0 - zi * zi; if (r2 < 0.0) r2 = 0.0;
        double ri = sqrt(r2);
        double th = (6.283185307179586 * (double)i) * phi;
        ws[W_TMPL + i * 3 + 0] = (float)(ri * cos(th));
        ws[W_TMPL + i * 3 + 1] = (float)(ri * sin(th));
        ws[W_TMPL + i * 3 + 2] = (float)zi;
    } else if (id < 298428) {
        int i = id - 298172; ws[W_SGH + i] = gh_g[i] / sqrtf(gh_v[i] + 1e-5f);
    } else if (id < 298684) {
        int i = id - 298428; ws[W_SC1 + i] = g1[i] / sqrtf(v1[i] + 1e-5f);
    } else if (id < 298984) {
        int i = id - 298684; ws[W_SC2 + i] = g2[i] / sqrtf(v2[i] + 1e-5f);
    } else if (id < 298988) {
        ((int*)(ws + W_CNT))[id - 298984] = 0;
    }
}

// ---------------- K1: fused stage A: h=relu(bn(W1 x)), graspable = W2 h + b2, masks ----------------
__global__ __launch_bounds__(256) void k1_stageA(
    const float* __restrict__ x,       // seed_features (B,256,20000)
    const float* __restrict__ wt,      // gh_w1^T [c][256]
    const float* __restrict__ b1g, const float* __restrict__ scg,
    const float* __restrict__ m1g, const float* __restrict__ be1g,
    const float* __restrict__ w2g, const float* __restrict__ b2g,   // (3,256),(3)
    float* __restrict__ out_grasp, float* __restrict__ out_obj, int* __restrict__ maskw) {
    __shared__ __align__(16) float Xs[256 * 32];
    __shared__ float Ssc[3 * 32];
    int b = blockIdx.y;
    int n0 = blockIdx.x * 32;
    int t = threadIdx.x;
    const float* xb = x + (size_t)b * CC * NN;
    // stage X tile [256 c][32 n]
    #pragma unroll
    for (int k = 0; k < 8; k++) {
        int f4 = t + k * 256; int c = f4 >> 3; int u = f4 & 7;
        float4 v = *(const float4*)(xb + (size_t)c * NN + n0 + u * 4);
        *(float4*)(Xs + c * 32 + u * 4) = v;
    }
    __syncthreads();
    int og = (t >> 3) * 8;
    int n4 = (t & 7) * 4;
    float acc[8][4] = {};
    #pragma unroll 4
    for (int c = 0; c < 256; c++) {
        float4 wva = *(const float4*)(wt + c * 256 + og);
        float4 wvb = *(const float4*)(wt + c * 256 + og + 4);
        float4 xv  = *(const float4*)(Xs + c * 32 + n4);
        float wr[8] = {wva.x, wva.y, wva.z, wva.w, wvb.x, wvb.y, wvb.z, wvb.w};
        float xr[4] = {xv.x, xv.y, xv.z, xv.w};
        #pragma unroll
        for (int i = 0; i < 8; i++)
            #pragma unroll
            for (int j = 0; j < 4; j++)
                acc[i][j] = fmaf(wr[i], xr[j], acc[i][j]);
    }
    __syncthreads();   // all reads of Xs done; reuse as h-tile
    #pragma unroll
    for (int i = 0; i < 8; i++) {
        int o = og + i;
        float bb = b1g[o], mm = m1g[o], ssv = scg[o], ee = be1g[o];
        float tmp[4];
        #pragma unroll
        for (int j = 0; j < 4; j++) {
            float y = __fadd_rn(acc[i][j], bb);
            y = __fadd_rn(__fmul_rn(__fsub_rn(y, mm), ssv), ee);
            tmp[j] = fmaxf(y, 0.0f);
        }
        *(float4*)(Xs + o * 32 + n4) = make_float4(tmp[0], tmp[1], tmp[2], tmp[3]);
    }
    __syncthreads();
    if (t < 96) {
        int v = t >> 5, n = t & 31;
        float a = 0.0f;
        for (int c = 0; c < 256; c++)
            a = fmaf(Xs[c * 32 + n], w2g[v * 256 + c], a);
        Ssc[v * 32 + n] = __fadd_rn(a, b2g[v]);
    }
    __syncthreads();
    if (t < 32) {
        int n = t;
        float s0 = Ssc[n], s1 = Ssc[32 + n], s2 = Ssc[64 + n];
        bool obj = s1 > s0;
        bool gr = obj && (s2 > 0.1f);
        int gn = b * NN + n0 + n;
        out_grasp[gn] = s2;
        out_obj[gn] = obj ? 1.0f : 0.0f;
        maskw[gn] = gr ? 1 : 0;
    }
}

// ---------------- K2: compact masked points ----------------
__global__ void k2_compact(const float* __restrict__ sx, const int* __restrict__ maskr,
                           int* __restrict__ cnt, float4* __restrict__ cpk) {
    int id = blockIdx.x * 256 + threadIdx.x;
    if (id >= BB * NN) return;
    int b = id / NN, n = id % NN;
    if (maskr[id]) {
        int pos = atomicAdd(cnt + b, 1);
        const float* p = sx + (size_t)id * 3;
        cpk[b * NN + pos] = make_float4(p[0], p[1], p[2], __uint_as_float((unsigned int)n));
    }
}

// ---------------- K3: FPS (one block per batch; PPT-templated self-selecting variants) ----------------
template <int PPT>
__global__ __launch_bounds__(512) void k3_fps(const float4* __restrict__ cpk,
                                              const int* __restrict__ cnt,
                                              float* __restrict__ out_inds,
                                              int* __restrict__ inds_i, int lo, int hi) {
    int b = blockIdx.x;
    int t = threadIdx.x;
    int M = cnt[b];
    int need = (M + 511) >> 9;
    if (!(need > lo && need <= hi)) return;   // exactly one variant proceeds per batch
    __shared__ float bcx, bcy, bcz;
    __shared__ unsigned int bcid;
    __shared__ unsigned long long wkey[8];
    __shared__ unsigned long long winkey;
    if (M == 0) {
        for (int s = t; s < SS; s += 512) { out_inds[b * SS + s] = 0.0f; inds_i[b * SS + s] = 0; }
        return;
    }
    float px[PPT], py[PPT], pz[PPT], dist[PPT];
    unsigned int pid[PPT];
    unsigned long long startkey = 0ull;
    float sbx = 0, sby = 0, sbz = 0; unsigned int sbid = 0;
    #pragma unroll
    for (int j = 0; j < PPT; j++) {
        int p = t + (j << 9);
        if (p < M) {
            float4 v = cpk[b * NN + p];
            px[j] = v.x; py[j] = v.y; pz[j] = v.z;
            pid[j] = __float_as_uint(v.w);
            dist[j] = 1e10f;
            unsigned long long k = (0xFFFFFFFFull << 32) | (unsigned int)(~pid[j]);
            if (k > startkey) { startkey = k; sbx = v.x; sby = v.y; sbz = v.z; sbid = pid[j]; }
        } else {
            px[j] = py[j] = pz[j] = 0.0f; dist[j] = -2.0f; pid[j] = 0u;
        }
    }
    int wid = t >> 6;
    { // block argmax for start = first masked index
        unsigned long long r = startkey;
        #pragma unroll
        for (int off = 32; off; off >>= 1) {
            unsigned long long o = __shfl_xor(r, off);
            if (o > r) r = o;
        }
        if ((t & 63) == 0) wkey[wid] = r;
        __syncthreads();
        if (t == 0) {
            unsigned long long w = 0ull;
            for (int i = 0; i < 8; i++) if (wkey[i] > w) w = wkey[i];
            winkey = w;
        }
        __syncthreads();
        if (startkey == winkey) { bcx = sbx; bcy = sby; bcz = sbz; bcid = sbid; }
        __syncthreads();
    }
    for (int step = 0; step < SS; step++) {
        float cx = bcx, cy = bcy, cz = bcz;
        unsigned int cid = bcid;
        if (t == 0) { out_inds[b * SS + step] = (float)cid; inds_i[b * SS + step] = (int)cid; }
        unsigned long long bkey = 0ull;
        float bx = 0, by = 0, bz = 0;
        #pragma unroll
        for (int j = 0; j < PPT; j++) {
            int p = t + (j << 9);
            if (p < M) {
                float dx = __fsub_rn(px[j], cx);
                float dy = __fsub_rn(py[j], cy);
                float dz = __fsub_rn(pz[j], cz);
                float d = __fadd_rn(__fadd_rn(__fmul_rn(dx, dx), __fmul_rn(dy, dy)), __fmul_rn(dz, dz));
                float nd = fminf(dist[j], d);
                dist[j] = nd;
                unsigned long long k = ((unsigned long long)fmono(nd) << 32) | (unsigned int)(~pid[j]);
                if (k > bkey) { bkey = k; bx = px[j]; by = py[j]; bz = pz[j]; }
            }
        }
        unsigned long long r = bkey;
        #pragma unroll
        for (int off = 32; off; off >>= 1) {
            unsigned long long o = __shfl_xor(r, off);
            if (o > r) r = o;
        }
        if ((t & 63) == 0) wkey[wid] = r;
        __syncthreads();
        if (t == 0) {
            unsigned long long w = 0ull;
            for (int i = 0; i < 8; i++) if (wkey[i] > w) w = wkey[i];
            winkey = w;
        }
        __syncthreads();
        if (bkey == winkey) {   // unique winner (key embeds unique orig idx)
            bcx = bx; bcy = by; bcz = bz;
            bcid = ~(unsigned int)(winkey & 0xFFFFFFFFull);
        }
        __syncthreads();
    }
}

// ---------------- K4: gathers ----------------
__global__ void k4_gather(const float* __restrict__ sx, const float* __restrict__ sf,
                          const int* __restrict__ inds, const float* __restrict__ grasp_all,
                          float* __restrict__ o_xyz, float* __restrict__ o_feat,
                          float* __restrict__ o_fg) {
    int id = blockIdx.x * 256 + threadIdx.x;   // 4096
    int b = id >> 10, s = id & 1023;
    int idx = inds[id];
    const float* p = sx + ((size_t)b * NN + idx) * 3;
    o_xyz[id * 3 + 0] = p[0];
    o_xyz[id * 3 + 1] = p[1];
    o_xyz[id * 3 + 2] = p[2];
    o_fg[id] = grasp_all[b * NN + idx];
    const float* fb = sf + (size_t)b * CC * NN + idx;
    float* ob = o_feat + (size_t)b * CC * SS + s;
    for (int c = 0; c < CC; c++)
        ob[c * SS] = fb[(size_t)c * NN];
}

// ---------------- K5: generic conv1x1 GEMM over 1024 pts (+optional bn+relu) ----------------
__global__ __launch_bounds__(256) void k5_gemm(const float* __restrict__ X, const float* __restrict__ WT,
                                               const float* __restrict__ bias, const float* __restrict__ scale,
                                               const float* __restrict__ mean, const float* __restrict__ beta,
                                               float* __restrict__ Y, int O, int Opad, int K, int relu_bn) {
    __shared__ __align__(16) float Xs[64 * 64];
    int b = blockIdx.z;
    int n0 = blockIdx.y * 64;
    int o0 = blockIdx.x * 64;
    int t = threadIdx.x;
    int o4 = o0 + (t & 15) * 4;
    int n4 = (t >> 4) * 4;
    float acc[4][4] = {};
    const float* Xb = X + (size_t)b * K * SS;
    for (int c0 = 0; c0 < K; c0 += 64) {
        #pragma unroll
        for (int k = 0; k < 4; k++) {
            int id = t + k * 256; int cc = id >> 4; int nn4 = (id & 15) * 4;
            int c = c0 + cc;
            float4 v = make_float4(0.f, 0.f, 0.f, 0.f);
            if (c < K) v = *(const float4*)(Xb + (size_t)c * SS + n0 + nn4);
            *(float4*)(Xs + cc * 64 + nn4) = v;
        }
        __syncthreads();
        int kmax = (K - c0 < 64) ? (K - c0) : 64;
        for (int cc = 0; cc < kmax; cc++) {
            float4 wv = *(const float4*)(WT + (size_t)(c0 + cc) * Opad + o4);
            float4 xv = *(const float4*)(Xs + cc * 64 + n4);
            float wr[4] = {wv.x, wv.y, wv.z, wv.w};
            float xr[4] = {xv.x, xv.y, xv.z, xv.w};
            #pragma unroll
            for (int i = 0; i < 4; i++)
                #pragma unroll
                for (int j = 0; j < 4; j++)
                    acc[i][j] = fmaf(wr[i], xr[j], acc[i][j]);
        }
        __syncthreads();
    }
    #pragma unroll
    for (int i = 0; i < 4; i++) {
        int o = o4 + i;
        if (o >= O) continue;
        float bb = bias[o];
        float val[4];
        if (relu_bn) {
            float ssv = scale[o], mm = mean[o], ee = beta[o];
            #pragma unroll
            for (int j = 0; j < 4; j++) {
                float y = __fadd_rn(acc[i][j], bb);
                y = __fadd_rn(__fmul_rn(__fsub_rn(y, mm), ssv), ee);
                val[j] = fmaxf(y, 0.0f);
            }
        } else {
            #pragma unroll
            for (int j = 0; j < 4; j++) val[j] = __fadd_rn(acc[i][j], bb);
        }
        *(float4*)(Y + ((size_t)b * O + o) * SS + n0 + n4) = make_float4(val[0], val[1], val[2], val[3]);
    }
}

// ---------------- K6: view max/argmax + templates + rotation matrices ----------------
__global__ void k6_view(const float* __restrict__ F3v, const float* __restrict__ tmpl,
                        float* __restrict__ o_ti, float* __restrict__ o_ts,
                        float* __restrict__ o_vx, float* __restrict__ o_vr) {
    int id = blockIdx.x * 256 + threadIdx.x;   // 4096
    int b = id >> 10, s = id & 1023;
    const float* f = F3v + (size_t)b * VV * SS + s;
    float best = f[0];
    int bi = 0;
    for (int v = 1; v < VV; v++) {
        float x = f[(size_t)v * SS];
        if (x > best) { best = x; bi = v; }
    }
    o_ti[id] = (float)bi;
    o_ts[id] = best;
    float tx = tmpl[bi * 3 + 0], ty = tmpl[bi * 3 + 1], tz = tmpl[bi * 3 + 2];
    o_vx[id * 3 + 0] = tx; o_vx[id * 3 + 1] = ty; o_vx[id * 3 + 2] = tz;
    // towards = -vp_xyz
    float ax0 = -tx, ax1 = -ty, ax2 = -tz;
    float ay0 = ty, ay1 = -tx, ay2 = 0.0f;   // (-ax1, ax0, 0)
    float ny = sqrtf(__fadd_rn(__fadd_rn(__fmul_rn(ay0, ay0), __fmul_rn(ay1, ay1)), __fmul_rn(ay2, ay2)));
    if (ny == 0.0f) { ay0 = 0.0f; ay1 = 1.0f; ay2 = 0.0f; }
    float nx = sqrtf(__fadd_rn(__fadd_rn(__fmul_rn(ax0, ax0), __fmul_rn(ax1, ax1)), __fmul_rn(ax2, ax2)));
    ax0 = ax0 / nx; ax1 = ax1 / nx; ax2 = ax2 / nx;
    float ny2 = sqrtf(__fadd_rn(__fadd_rn(__fmul_rn(ay0, ay0), __fmul_rn(ay1, ay1)), __fmul_rn(ay2, ay2)));
    ay0 = ay0 / ny2; ay1 = ay1 / ny2; ay2 = ay2 / ny2;
    float az0 = __fsub_rn(__fmul_rn(ax1, ay2), __fmul_rn(ax2, ay1));
    float az1 = __fsub_rn(__fmul_rn(ax2, ay0), __fmul_rn(ax0, ay2));
    float az2 = __fsub_rn(__fmul_rn(ax0, ay1), __fmul_rn(ax1, ay0));
    float* R = o_vr + (size_t)id * 9;   // columns = (ax, ay, az)
    R[0] = ax0; R[1] = ay0; R[2] = az0;
    R[3] = ax1; R[4] = ay1; R[5] = az1;
    R[6] = ax2; R[7] = ay2; R[8] = az2;
}

// ---------------- K7: transpose f3 (B,300,1024) -> view_score (B,1024,300) ----------------
__global__ void k7_transpose(const float* __restrict__ F3v, float* __restrict__ outp) {
    __shared__ float T[64][65];
    int b = blockIdx.z;
    int s0 = blockIdx.y * 64;
    int v0 = blockIdx.x * 64;
    int t = threadIdx.x;
    int sc = t & 63;
    int g = t >> 6;
    #pragma unroll
    for (int k = 0; k < 16; k++) {
        int vr = g * 16 + k;
        int v = v0 + vr;
        T[vr][sc] = (v < VV) ? F3v[((size_t)b * VV + v) * SS + s0 + sc] : 0.0f;
    }
    __syncthreads();
    #pragma unroll
    for (int k = 0; k < 16; k++) {
        int sr = g * 16 + k;
        int v = v0 + sc;
        if (v < VV)
            outp[((size_t)b * SS + (s0 + sr)) * VV + v] = T[sc][sr];
    }
}

extern "C" void kernel_launch(void* const* d_in, const int* in_sizes, int n_in,
                              void* d_out, int out_size, void* d_ws, size_t ws_size,
                              hipStream_t stream) {
    const float* seed_xyz  = (const float*)d_in[0];
    const float* seed_feat = (const float*)d_in[1];
    const float* gh_w1 = (const float*)d_in[2];
    const float* gh_b1 = (const float*)d_in[3];
    const float* gh_g1 = (const float*)d_in[4];
    const float* gh_be1 = (const float*)d_in[5];
    const float* gh_m1 = (const float*)d_in[6];
    const float* gh_v1 = (const float*)d_in[7];
    const float* gh_w2 = (const float*)d_in[8];
    const float* gh_b2 = (const float*)d_in[9];
    const float* w1 = (const float*)d_in[10];
    const float* b1 = (const float*)d_in[11];
    const float* g1 = (const float*)d_in[12];
    const float* be1 = (const float*)d_in[13];
    const float* m1 = (const float*)d_in[14];
    const float* v1 = (const float*)d_in[15];
    const float* w2 = (const float*)d_in[16];
    const float* b2 = (const float*)d_in[17];
    const float* g2 = (const float*)d_in[18];
    const float* be2 = (const float*)d_in[19];
    const float* m2 = (const float*)d_in[20];
    const float* v2 = (const float*)d_in[21];
    const float* w3 = (const float*)d_in[22];
    const float* b3 = (const float*)d_in[23];

    float* out = (float*)d_out;
    float* ws = (float*)d_ws;
    int* cnt = (int*)(ws + W_CNT);
    float4* cpk = (float4*)(ws + W_CPK);
    int* inds_i = (int*)(ws + W_INDS);
    int* maskw = (int*)(ws + W_MASK);

    // K0: prep
    k0_prep<<<dim3((298988 + 255) / 256), dim3(256), 0, stream>>>(
        gh_w1, w1, w2, w3, gh_g1, gh_v1, g1, v1, g2, v2, ws);

    // K1: fused stage A
    k1_stageA<<<dim3(NN / 32, BB), dim3(256), 0, stream>>>(
        seed_feat, ws + W_GH1T, gh_b1, ws + W_SGH, gh_m1, gh_be1, gh_w2, gh_b2,
        out + O_GRASP, out + O_OBJ, maskw);

    // K2: compaction
    k2_compact<<<dim3((BB * NN + 255) / 256), dim3(256), 0, stream>>>(seed_xyz, maskw, cnt, cpk);

    // K3: FPS (three self-selecting register-capacity variants)
    k3_fps<13><<<dim3(BB), dim3(512), 0, stream>>>(cpk, cnt, out + O_INDS, inds_i, -1, 13);
    k3_fps<26><<<dim3(BB), dim3(512), 0, stream>>>(cpk, cnt, out + O_INDS, inds_i, 13, 26);
    k3_fps<40><<<dim3(BB), dim3(512), 0, stream>>>(cpk, cnt, out + O_INDS, inds_i, 26, 40);

    // K4: gathers (xyz, features, graspness)
    k4_gather<<<dim3(BB * SS / 256), dim3(256), 0, stream>>>(
        seed_xyz, seed_feat, inds_i, out + O_GRASP, out + O_GXYZ, out + O_GFEAT, out + O_FPG);

    // K5: stage C MLP (three conv1x1 layers)
    k5_gemm<<<dim3(4, 16, BB), dim3(256), 0, stream>>>(
        out + O_GFEAT, ws + W_W1T, b1, ws + W_SC1, m1, be1, ws + W_F1, 256, 256, 256, 1);
    k5_gemm<<<dim3(5, 16, BB), dim3(256), 0, stream>>>(
        ws + W_F1, ws + W_W2T, b2, ws + W_SC2, m2, be2, ws + W_F2, 300, 320, 256, 1);
    k5_gemm<<<dim3(5, 16, BB), dim3(256), 0, stream>>>(
        ws + W_F2, ws + W_W3T, b3, b3, b3, b3, ws + W_F3, 300, 320, 300, 0);

    // K6: view argmax + rotations
    k6_view<<<dim3(BB * SS / 256), dim3(256), 0, stream>>>(
        ws + W_F3, ws + W_TMPL, out + O_TVI, out + O_TVS, out + O_VPX, out + O_VPR);

    // K7: view_score transpose
    k7_transpose<<<dim3(5, 16, BB), dim3(256), 0, stream>>>(ws + W_F3, out + O_VIEW);
}

// Round 2
// 1665.705 us; speedup vs baseline: 1.1254x; 1.1254x over previous
//
#include <hip/hip_runtime.h>
#include <math.h>

// ---------------- problem constants ----------------
#define BB 4
#define NN 20000
#define CC 256
#define VV 300
#define SS 1024

// output float offsets (concatenated flat, all read back as float32)
#define O_GRASP   0          // (4,20000)
#define O_OBJ     80000      // (4,20000)
#define O_GXYZ    160000     // (4,1024,3)
#define O_INDS    172288     // (4,1024)
#define O_GFEAT   176384     // (4,256,1024)
#define O_FPG     1224960    // (4,1024)
#define O_VIEW    1229056    // (4,1024,300)
#define O_TVI     2457856    // (4,1024)
#define O_TVS     2461952    // (4,1024)
#define O_VPX     2466048    // (4,1024,3)
#define O_VPR     2478336    // (4,1024,3,3)

// ws float offsets
#define W_GH1T    0          // [256 c][256 o]
#define W_W1T     65536      // [256 c][256 o]
#define W_W2T     131072     // [256 c][320 o-pad] (O=300)
#define W_W3T     212992     // [300 c][320 o-pad] (O=300)
#define W_TMPL    308992     // 300*3
#define W_SGH     309892     // 256
#define W_SC1     310148     // 256
#define W_SC2     310404     // 300
#define W_CNT     310704     // 4 ints (pad to 310720)
#define W_CPK     310720     // 4*20000 float4 (x,y,z,idx-bits)
#define W_INDS    630720     // 4*1024 int
#define W_MASK    634816     // 4*20000 int
#define W_F1      714816     // 4*256*1024
#define W_F2      1763392    // 4*300*1024
#define W_F3      2992192    // 4*300*1024  (end 4220992 floats = 16.9 MB)

__device__ __forceinline__ unsigned int fmono(float f) {
    unsigned int u = __float_as_uint(f);
    return (u & 0x80000000u) ? ~u : (u | 0x80000000u);
}

// ---- DPP-based wave64 max reduction on u64 keys (result broadcast to all lanes) ----
template <int CTRL>
__device__ __forceinline__ unsigned long long wmax_step(unsigned long long k) {
    int lo = (int)(unsigned int)k;
    int hi = (int)(unsigned int)(k >> 32);
    int plo = __builtin_amdgcn_update_dpp(lo, lo, CTRL, 0xf, 0xf, false);
    int phi = __builtin_amdgcn_update_dpp(hi, hi, CTRL, 0xf, 0xf, false);
    unsigned long long p = ((unsigned long long)(unsigned int)phi << 32) | (unsigned int)plo;
    return (p > k) ? p : k;
}
__device__ __forceinline__ unsigned long long wave_max_u64(unsigned long long k) {
    k = wmax_step<0x111>(k);   // row_shr:1
    k = wmax_step<0x112>(k);   // row_shr:2
    k = wmax_step<0x114>(k);   // row_shr:4
    k = wmax_step<0x118>(k);   // row_shr:8  -> lane15 of each row has row max
    k = wmax_step<0x142>(k);   // row_bcast15
    k = wmax_step<0x143>(k);   // row_bcast31 -> lane63 has wave max
    unsigned int lo = (unsigned int)__builtin_amdgcn_readlane((int)(unsigned int)k, 63);
    unsigned int hi = (unsigned int)__builtin_amdgcn_readlane((int)(unsigned int)(k >> 32), 63);
    return ((unsigned long long)hi << 32) | lo;
}

// ---------------- K0: prep (transposes, bn scales, templates, cnt=0) ----------------
__global__ void k0_prep(const float* __restrict__ w_gh1, const float* __restrict__ w1,
                        const float* __restrict__ w2, const float* __restrict__ w3,
                        const float* __restrict__ gh_g, const float* __restrict__ gh_v,
                        const float* __restrict__ g1, const float* __restrict__ v1,
                        const float* __restrict__ g2, const float* __restrict__ v2,
                        float* __restrict__ ws) {
    int id = blockIdx.x * 256 + threadIdx.x;
    if (id < 65536) {
        int k = id & 255, o = id >> 8;
        ws[W_GH1T + k * 256 + o] = w_gh1[id];
    } else if (id < 131072) {
        int l = id - 65536; int k = l & 255, o = l >> 8;
        ws[W_W1T + k * 256 + o] = w1[l];
    } else if (id < 207872) {
        int l = id - 131072; int k = l & 255, o = l >> 8;
        ws[W_W2T + k * 320 + o] = w2[l];
    } else if (id < 297872) {
        int l = id - 207872; int k = l % 300, o = l / 300;
        ws[W_W3T + k * 320 + o] = w3[l];
    } else if (id < 298172) {
        int i = id - 297872;
        double phi = (sqrt(5.0) - 1.0) / 2.0;
        double zi = (2.0 * (double)i + 1.0) / 300.0 - 1.0;
        double r2 = 1.0 - zi * zi; if (r2 < 0.0) r2 = 0.0;
        double ri = sqrt(r2);
        double th = (6.283185307179586 * (double)i) * phi;
        ws[W_TMPL + i * 3 + 0] = (float)(ri * cos(th));
        ws[W_TMPL + i * 3 + 1] = (float)(ri * sin(th));
        ws[W_TMPL + i * 3 + 2] = (float)zi;
    } else if (id < 298428) {
        int i = id - 298172; ws[W_SGH + i] = gh_g[i] / sqrtf(gh_v[i] + 1e-5f);
    } else if (id < 298684) {
        int i = id - 298428; ws[W_SC1 + i] = g1[i] / sqrtf(v1[i] + 1e-5f);
    } else if (id < 298984) {
        int i = id - 298684; ws[W_SC2 + i] = g2[i] / sqrtf(v2[i] + 1e-5f);
    } else if (id < 298988) {
        ((int*)(ws + W_CNT))[id - 298984] = 0;
    }
}

// ---------------- K1: fused stage A (64-wide n-tile) ----------------
// h = relu(bn(W1 x)); graspable = W2 h + b2; masks. Accumulation order identical
// to the verified round-1 kernel (serial ascending c, bias added last).
__global__ __launch_bounds__(256) void k1_stageA(
    const float* __restrict__ x,       // seed_features (B,256,20000)
    const float* __restrict__ wt,      // gh_w1^T [c][256]
    const float* __restrict__ b1g, const float* __restrict__ scg,
    const float* __restrict__ m1g, const float* __restrict__ be1g,
    const float* __restrict__ w2g, const float* __restrict__ b2g,   // (3,256),(3)
    float* __restrict__ out_grasp, float* __restrict__ out_obj, int* __restrict__ maskw) {
    __shared__ __align__(16) float Xs[256 * 64];   // 64 KB
    int b = blockIdx.y;
    int n0 = blockIdx.x * 64;
    int t = threadIdx.x;
    const float* xb = x + (size_t)b * CC * NN;
    #pragma unroll
    for (int k = 0; k < 16; k++) {
        int id = t + k * 256; int c = id >> 4; int u = id & 15;
        int n = n0 + u * 4;
        float4 v = make_float4(0.f, 0.f, 0.f, 0.f);
        if (n < NN) v = *(const float4*)(xb + (size_t)c * NN + n);
        *(float4*)(Xs + c * 64 + u * 4) = v;
    }
    __syncthreads();
    int og = (t >> 3) * 8;
    int n8 = (t & 7) * 8;
    float acc[8][8] = {};
    #pragma unroll 2
    for (int c = 0; c < 256; c++) {
        float4 wva = *(const float4*)(wt + c * 256 + og);
        float4 wvb = *(const float4*)(wt + c * 256 + og + 4);
        float4 xva = *(const float4*)(Xs + c * 64 + n8);
        float4 xvb = *(const float4*)(Xs + c * 64 + n8 + 4);
        float wr[8] = {wva.x, wva.y, wva.z, wva.w, wvb.x, wvb.y, wvb.z, wvb.w};
        float xr[8] = {xva.x, xva.y, xva.z, xva.w, xvb.x, xvb.y, xvb.z, xvb.w};
        #pragma unroll
        for (int i = 0; i < 8; i++)
            #pragma unroll
            for (int j = 0; j < 8; j++)
                acc[i][j] = fmaf(wr[i], xr[j], acc[i][j]);
    }
    __syncthreads();   // all reads of Xs done; reuse as h-tile
    #pragma unroll
    for (int i = 0; i < 8; i++) {
        int o = og + i;
        float bb = b1g[o], mm = m1g[o], ssv = scg[o], ee = be1g[o];
        float tmp[8];
        #pragma unroll
        for (int j = 0; j < 8; j++) {
            float y = __fadd_rn(acc[i][j], bb);
            y = __fadd_rn(__fmul_rn(__fsub_rn(y, mm), ssv), ee);
            tmp[j] = fmaxf(y, 0.0f);
        }
        *(float4*)(Xs + o * 64 + n8)     = make_float4(tmp[0], tmp[1], tmp[2], tmp[3]);
        *(float4*)(Xs + o * 64 + n8 + 4) = make_float4(tmp[4], tmp[5], tmp[6], tmp[7]);
    }
    __syncthreads();
    if (t < 64) {
        float s0a = 0.0f, s1a = 0.0f, s2a = 0.0f;
        for (int c = 0; c < 256; c++) {
            float xv = Xs[c * 64 + t];
            s0a = fmaf(xv, w2g[c], s0a);
            s1a = fmaf(xv, w2g[256 + c], s1a);
            s2a = fmaf(xv, w2g[512 + c], s2a);
        }
        int n = n0 + t;
        if (n < NN) {
            float s0 = __fadd_rn(s0a, b2g[0]);
            float s1 = __fadd_rn(s1a, b2g[1]);
            float s2 = __fadd_rn(s2a, b2g[2]);
            bool obj = s1 > s0;
            bool gr = obj && (s2 > 0.1f);
            int gn = b * NN + n;
            out_grasp[gn] = s2;
            out_obj[gn] = obj ? 1.0f : 0.0f;
            maskw[gn] = gr ? 1 : 0;
        }
    }
}

// ---------------- K2: compact masked points ----------------
__global__ void k2_compact(const float* __restrict__ sx, const int* __restrict__ maskr,
                           int* __restrict__ cnt, float4* __restrict__ cpk) {
    int id = blockIdx.x * 256 + threadIdx.x;
    if (id >= BB * NN) return;
    int b = id / NN, n = id % NN;
    if (maskr[id]) {
        int pos = atomicAdd(cnt + b, 1);
        const float* p = sx + (size_t)id * 3;
        cpk[b * NN + pos] = make_float4(p[0], p[1], p[2], __uint_as_float((unsigned int)n));
    }
}

// ---------------- K3: FPS — 1 barrier/step, DPP wave reduce, dbuf winner slots ----------------
template <int PPT>
__global__ __launch_bounds__(512) void k3_fps(const float4* __restrict__ cpk,
                                              const int* __restrict__ cnt,
                                              float* __restrict__ out_inds,
                                              int* __restrict__ inds_i, int lo, int hi) {
    int b = blockIdx.x;
    int t = threadIdx.x;
    int M = cnt[b];
    int need = (M + 511) >> 9;
    if (!(need > lo && need <= hi)) return;   // exactly one variant proceeds per batch
    __shared__ unsigned long long skey[2][8];
    __shared__ __align__(16) float4 scd[2][8];
    if (M == 0) {
        for (int s = t; s < SS; s += 512) { out_inds[b * SS + s] = 0.0f; inds_i[b * SS + s] = 0; }
        return;
    }
    float px[PPT], py[PPT], pz[PPT], dist[PPT];
    unsigned int pid[PPT];
    int wid = t >> 6, lane = t & 63;
    unsigned long long bkey = 0ull;
    float bx = 0, by = 0, bz = 0;
    #pragma unroll
    for (int j = 0; j < PPT; j++) {
        int p = t + (j << 9);
        if (p < M) {
            float4 v = cpk[b * NN + p];
            px[j] = v.x; py[j] = v.y; pz[j] = v.z;
            pid[j] = __float_as_uint(v.w);
            dist[j] = 1e10f;
            unsigned long long k = (0xFFFFFFFFull << 32) | (unsigned int)(~pid[j]);
            if (k > bkey) { bkey = k; bx = v.x; by = v.y; bz = v.z; }
        } else {
            px[j] = py[j] = pz[j] = 0.0f; dist[j] = 0.0f; pid[j] = 0u;
        }
    }
    // publish initial winner (start = first masked index)
    {
        unsigned long long wkey = wave_max_u64(bkey);
        unsigned long long mb = __ballot(bkey == wkey);
        if (lane == __ffsll((long long)mb) - 1) {
            skey[0][wid] = wkey;
            scd[0][wid] = make_float4(bx, by, bz, 0.0f);
        }
    }
    __syncthreads();
    int buf = 0;
    for (int step = 0; step < SS; step++) {
        // combine the 8 wave slots (broadcast LDS reads, done by every thread)
        unsigned long long wk = skey[buf][0];
        float4 c = scd[buf][0];
        #pragma unroll
        for (int i = 1; i < 8; i++) {
            unsigned long long k2 = skey[buf][i];
            float4 c2 = scd[buf][i];
            if (k2 > wk) { wk = k2; c = c2; }
        }
        unsigned int cid = ~(unsigned int)(wk & 0xFFFFFFFFull);
        if (t == 0) { out_inds[b * SS + step] = (float)cid; inds_i[b * SS + step] = (int)cid; }
        // distance update + per-lane best
        bkey = 0ull; bx = by = bz = 0.0f;
        #pragma unroll
        for (int j = 0; j < PPT; j++) {
            int p = t + (j << 9);
            if (p < M) {
                float dx = __fsub_rn(px[j], c.x);
                float dy = __fsub_rn(py[j], c.y);
                float dz = __fsub_rn(pz[j], c.z);
                float d = __fadd_rn(__fadd_rn(__fmul_rn(dx, dx), __fmul_rn(dy, dy)), __fmul_rn(dz, dz));
                float nd = fminf(dist[j], d);
                dist[j] = nd;
                // nd >= 0 always -> monotone key is just (bits | signbit)
                unsigned long long k = ((unsigned long long)(__float_as_uint(nd) | 0x80000000u) << 32)
                                       | (unsigned int)(~pid[j]);
                if (k > bkey) { bkey = k; bx = px[j]; by = py[j]; bz = pz[j]; }
            }
        }
        unsigned long long wkey = wave_max_u64(bkey);
        unsigned long long mb = __ballot(bkey == wkey);
        if (lane == __ffsll((long long)mb) - 1) {
            skey[buf ^ 1][wid] = wkey;
            scd[buf ^ 1][wid] = make_float4(bx, by, bz, 0.0f);
        }
        __syncthreads();
        buf ^= 1;
    }
}

// ---------------- K4a: feature gather (one thread per output element) ----------------
__global__ void k4_gatherF(const float* __restrict__ sf, const int* __restrict__ inds,
                           float* __restrict__ o_feat) {
    int id = blockIdx.x * 256 + threadIdx.x;   // B*C*S = 1,048,576
    int s = id & (SS - 1);
    int bc = id >> 10;                          // b*C + c
    int b = bc >> 8;
    int idx = inds[(b << 10) | s];
    o_feat[id] = sf[(size_t)bc * NN + idx];
}

// ---------------- K4b: xyz + graspness gather ----------------
__global__ void k4_gatherX(const float* __restrict__ sx, const int* __restrict__ inds,
                           const float* __restrict__ grasp_all,
                           float* __restrict__ o_xyz, float* __restrict__ o_fg) {
    int id = blockIdx.x * 256 + threadIdx.x;   // 4096
    int b = id >> 10;
    int idx = inds[id];
    const float* p = sx + ((size_t)b * NN + idx) * 3;
    o_xyz[id * 3 + 0] = p[0];
    o_xyz[id * 3 + 1] = p[1];
    o_xyz[id * 3 + 2] = p[2];
    o_fg[id] = grasp_all[b * NN + idx];
}

// ---------------- K5: generic conv1x1 GEMM over 1024 pts (+optional bn+relu) ----------------
__global__ __launch_bounds__(256) void k5_gemm(const float* __restrict__ X, const float* __restrict__ WT,
                                               const float* __restrict__ bias, const float* __restrict__ scale,
                                               const float* __restrict__ mean, const float* __restrict__ beta,
                                               float* __restrict__ Y, int O, int Opad, int K, int relu_bn) {
    __shared__ __align__(16) float Xs[64 * 64];
    int b = blockIdx.z;
    int n0 = blockIdx.y * 64;
    int o0 = blockIdx.x * 64;
    int t = threadIdx.x;
    int o4 = o0 + (t & 15) * 4;
    int n4 = (t >> 4) * 4;
    float acc[4][4] = {};
    const float* Xb = X + (size_t)b * K * SS;
    for (int c0 = 0; c0 < K; c0 += 64) {
        #pragma unroll
        for (int k = 0; k < 4; k++) {
            int id = t + k * 256; int cc = id >> 4; int nn4 = (id & 15) * 4;
            int c = c0 + cc;
            float4 v = make_float4(0.f, 0.f, 0.f, 0.f);
            if (c < K) v = *(const float4*)(Xb + (size_t)c * SS + n0 + nn4);
            *(float4*)(Xs + cc * 64 + nn4) = v;
        }
        __syncthreads();
        int kmax = (K - c0 < 64) ? (K - c0) : 64;
        for (int cc = 0; cc < kmax; cc++) {
            float4 wv = *(const float4*)(WT + (size_t)(c0 + cc) * Opad + o4);
            float4 xv = *(const float4*)(Xs + cc * 64 + n4);
            float wr[4] = {wv.x, wv.y, wv.z, wv.w};
            float xr[4] = {xv.x, xv.y, xv.z, xv.w};
            #pragma unroll
            for (int i = 0; i < 4; i++)
                #pragma unroll
                for (int j = 0; j < 4; j++)
                    acc[i][j] = fmaf(wr[i], xr[j], acc[i][j]);
        }
        __syncthreads();
    }
    #pragma unroll
    for (int i = 0; i < 4; i++) {
        int o = o4 + i;
        if (o >= O) continue;
        float bb = bias[o];
        float val[4];
        if (relu_bn) {
            float ssv = scale[o], mm = mean[o], ee = beta[o];
            #pragma unroll
            for (int j = 0; j < 4; j++) {
                float y = __fadd_rn(acc[i][j], bb);
                y = __fadd_rn(__fmul_rn(__fsub_rn(y, mm), ssv), ee);
                val[j] = fmaxf(y, 0.0f);
            }
        } else {
            #pragma unroll
            for (int j = 0; j < 4; j++) val[j] = __fadd_rn(acc[i][j], bb);
        }
        *(float4*)(Y + ((size_t)b * O + o) * SS + n0 + n4) = make_float4(val[0], val[1], val[2], val[3]);
    }
}

// ---------------- K6: view max/argmax (4-way parallel over V) + rotations ----------------
__global__ void k6_view(const float* __restrict__ F3v, const float* __restrict__ tmpl,
                        float* __restrict__ o_ti, float* __restrict__ o_ts,
                        float* __restrict__ o_vx, float* __restrict__ o_vr) {
    __shared__ float sv[4][64];
    __shared__ int si[4][64];
    int blk = blockIdx.x;                 // 64 blocks
    int b = blk >> 4;
    int s0 = (blk & 15) << 6;
    int t = threadIdx.x;
    int sl = t & 63, g = t >> 6;
    const float* f = F3v + (size_t)b * VV * SS + s0 + sl;
    int v0 = g * 75;
    float best = f[(size_t)v0 * SS];
    int bi = v0;
    for (int v = v0 + 1; v < v0 + 75; v++) {
        float x = f[(size_t)v * SS];
        if (x > best) { best = x; bi = v; }   // strict > keeps first max
    }
    sv[g][sl] = best; si[g][sl] = bi;
    __syncthreads();
    if (t < 64) {
        float bv = sv[0][t]; int bix = si[0][t];
        #pragma unroll
        for (int g2 = 1; g2 < 4; g2++) {
            float x = sv[g2][t];
            if (x > bv) { bv = x; bix = si[g2][t]; }   // ties -> earlier group (smaller v)
        }
        int id = (b << 10) + s0 + t;
        o_ti[id] = (float)bix;
        o_ts[id] = bv;
        float tx = tmpl[bix * 3 + 0], ty = tmpl[bix * 3 + 1], tz = tmpl[bix * 3 + 2];
        o_vx[id * 3 + 0] = tx; o_vx[id * 3 + 1] = ty; o_vx[id * 3 + 2] = tz;
        // towards = -vp_xyz
        float ax0 = -tx, ax1 = -ty, ax2 = -tz;
        float ay0 = ty, ay1 = -tx, ay2 = 0.0f;   // (-ax1, ax0, 0)
        float ny = sqrtf(__fadd_rn(__fadd_rn(__fmul_rn(ay0, ay0), __fmul_rn(ay1, ay1)), __fmul_rn(ay2, ay2)));
        if (ny == 0.0f) { ay0 = 0.0f; ay1 = 1.0f; ay2 = 0.0f; }
        float nx = sqrtf(__fadd_rn(__fadd_rn(__fmul_rn(ax0, ax0), __fmul_rn(ax1, ax1)), __fmul_rn(ax2, ax2)));
        ax0 = ax0 / nx; ax1 = ax1 / nx; ax2 = ax2 / nx;
        float ny2 = sqrtf(__fadd_rn(__fadd_rn(__fmul_rn(ay0, ay0), __fmul_rn(ay1, ay1)), __fmul_rn(ay2, ay2)));
        ay0 = ay0 / ny2; ay1 = ay1 / ny2; ay2 = ay2 / ny2;
        float az0 = __fsub_rn(__fmul_rn(ax1, ay2), __fmul_rn(ax2, ay1));
        float az1 = __fsub_rn(__fmul_rn(ax2, ay0), __fmul_rn(ax0, ay2));
        float az2 = __fsub_rn(__fmul_rn(ax0, ay1), __fmul_rn(ax1, ay0));
        float* R = o_vr + (size_t)id * 9;   // columns = (ax, ay, az)
        R[0] = ax0; R[1] = ay0; R[2] = az0;
        R[3] = ax1; R[4] = ay1; R[5] = az1;
        R[6] = ax2; R[7] = ay2; R[8] = az2;
    }
}

// ---------------- K7: transpose f3 (B,300,1024) -> view_score (B,1024,300) ----------------
__global__ void k7_transpose(const float* __restrict__ F3v, float* __restrict__ outp) {
    __shared__ float T[64][65];
    int b = blockIdx.z;
    int s0 = blockIdx.y * 64;
    int v0 = blockIdx.x * 64;
    int t = threadIdx.x;
    int sc = t & 63;
    int g = t >> 6;
    #pragma unroll
    for (int k = 0; k < 16; k++) {
        int vr = g * 16 + k;
        int v = v0 + vr;
        T[vr][sc] = (v < VV) ? F3v[((size_t)b * VV + v) * SS + s0 + sc] : 0.0f;
    }
    __syncthreads();
    #pragma unroll
    for (int k = 0; k < 16; k++) {
        int sr = g * 16 + k;
        int v = v0 + sc;
        if (v < VV)
            outp[((size_t)b * SS + (s0 + sr)) * VV + v] = T[sc][sr];
    }
}

extern "C" void kernel_launch(void* const* d_in, const int* in_sizes, int n_in,
                              void* d_out, int out_size, void* d_ws, size_t ws_size,
                              hipStream_t stream) {
    const float* seed_xyz  = (const float*)d_in[0];
    const float* seed_feat = (const float*)d_in[1];
    const float* gh_w1 = (const float*)d_in[2];
    const float* gh_b1 = (const float*)d_in[3];
    const float* gh_g1 = (const float*)d_in[4];
    const float* gh_be1 = (const float*)d_in[5];
    const float* gh_m1 = (const float*)d_in[6];
    const float* gh_v1 = (const float*)d_in[7];
    const float* gh_w2 = (const float*)d_in[8];
    const float* gh_b2 = (const float*)d_in[9];
    const float* w1 = (const float*)d_in[10];
    const float* b1 = (const float*)d_in[11];
    const float* g1 = (const float*)d_in[12];
    const float* be1 = (const float*)d_in[13];
    const float* m1 = (const float*)d_in[14];
    const float* v1 = (const float*)d_in[15];
    const float* w2 = (const float*)d_in[16];
    const float* b2 = (const float*)d_in[17];
    const float* g2 = (const float*)d_in[18];
    const float* be2 = (const float*)d_in[19];
    const float* m2 = (const float*)d_in[20];
    const float* v2 = (const float*)d_in[21];
    const float* w3 = (const float*)d_in[22];
    const float* b3 = (const float*)d_in[23];

    float* out = (float*)d_out;
    float* ws = (float*)d_ws;
    int* cnt = (int*)(ws + W_CNT);
    float4* cpk = (float4*)(ws + W_CPK);
    int* inds_i = (int*)(ws + W_INDS);
    int* maskw = (int*)(ws + W_MASK);

    // K0: prep
    k0_prep<<<dim3((298988 + 255) / 256), dim3(256), 0, stream>>>(
        gh_w1, w1, w2, w3, gh_g1, gh_v1, g1, v1, g2, v2, ws);

    // K1: fused stage A (64-wide tiles)
    k1_stageA<<<dim3((NN + 63) / 64, BB), dim3(256), 0, stream>>>(
        seed_feat, ws + W_GH1T, gh_b1, ws + W_SGH, gh_m1, gh_be1, gh_w2, gh_b2,
        out + O_GRASP, out + O_OBJ, maskw);

    // K2: compaction
    k2_compact<<<dim3((BB * NN + 255) / 256), dim3(256), 0, stream>>>(seed_xyz, maskw, cnt, cpk);

    // K3: FPS (three self-selecting register-capacity variants)
    k3_fps<13><<<dim3(BB), dim3(512), 0, stream>>>(cpk, cnt, out + O_INDS, inds_i, -1, 13);
    k3_fps<26><<<dim3(BB), dim3(512), 0, stream>>>(cpk, cnt, out + O_INDS, inds_i, 13, 26);
    k3_fps<40><<<dim3(BB), dim3(512), 0, stream>>>(cpk, cnt, out + O_INDS, inds_i, 26, 40);

    // K4: gathers
    k4_gatherF<<<dim3(BB * CC * SS / 256), dim3(256), 0, stream>>>(seed_feat, inds_i, out + O_GFEAT);
    k4_gatherX<<<dim3(BB * SS / 256), dim3(256), 0, stream>>>(
        seed_xyz, inds_i, out + O_GRASP, out + O_GXYZ, out + O_FPG);

    // K5: stage C MLP (three conv1x1 layers)
    k5_gemm<<<dim3(4, 16, BB), dim3(256), 0, stream>>>(
        out + O_GFEAT, ws + W_W1T, b1, ws + W_SC1, m1, be1, ws + W_F1, 256, 256, 256, 1);
    k5_gemm<<<dim3(5, 16, BB), dim3(256), 0, stream>>>(
        ws + W_F1, ws + W_W2T, b2, ws + W_SC2, m2, be2, ws + W_F2, 300, 320, 256, 1);
    k5_gemm<<<dim3(5, 16, BB), dim3(256), 0, stream>>>(
        ws + W_F2, ws + W_W3T, b3, b3, b3, b3, ws + W_F3, 300, 320, 300, 0);

    // K6: view argmax + rotations
    k6_view<<<dim3(64), dim3(256), 0, stream>>>(
        ws + W_F3, ws + W_TMPL, out + O_TVI, out + O_TVS, out + O_VPX, out + O_VPR);

    // K7: view_score transpose
    k7_transpose<<<dim3(5, 16, BB), dim3(256), 0, stream>>>(ws + W_F3, out + O_VIEW);
}

// Round 3
// 1663.398 us; speedup vs baseline: 1.1269x; 1.0014x over previous
//
#include <hip/hip_runtime.h>
#include <math.h>

// ---------------- problem constants ----------------
#define BB 4
#define NN 20000
#define CC 256
#define VV 300
#define SS 1024

// output float offsets (concatenated flat, all read back as float32)
#define O_GRASP   0          // (4,20000)
#define O_OBJ     80000      // (4,20000)
#define O_GXYZ    160000     // (4,1024,3)
#define O_INDS    172288     // (4,1024)
#define O_GFEAT   176384     // (4,256,1024)
#define O_FPG     1224960    // (4,1024)
#define O_VIEW    1229056    // (4,1024,300)
#define O_TVI     2457856    // (4,1024)
#define O_TVS     2461952    // (4,1024)
#define O_VPX     2466048    // (4,1024,3)
#define O_VPR     2478336    // (4,1024,3,3)

// ws float offsets
#define W_GH1T    0          // [256 c][256 o]
#define W_W1T     65536      // [256 c][256 o]
#define W_W2T     131072     // [256 c][320 o-pad] (O=300)
#define W_W3T     212992     // [300 c][320 o-pad] (O=300)
#define W_TMPL    308992     // 300*3
#define W_SGH     309892     // 256
#define W_SC1     310148     // 256
#define W_SC2     310404     // 300
#define W_CNT     310704     // 4 ints (pad to 310720)
#define W_CPK     310720     // 4*20000 float4 (x,y,z,idx-bits)
#define W_INDS    630720     // 4*1024 int
#define W_MASK    634816     // 4*20000 int
#define W_F1      714816     // 4*256*1024
#define W_F2      1763392    // 4*300*1024
#define W_F3      2992192    // 4*300*1024  (end 4220992 floats = 16.9 MB)

// ---- DPP-based wave64 max reduction on u64 keys (result broadcast to all lanes) ----
template <int CTRL>
__device__ __forceinline__ unsigned long long wmax_step(unsigned long long k) {
    int lo = (int)(unsigned int)k;
    int hi = (int)(unsigned int)(k >> 32);
    int plo = __builtin_amdgcn_update_dpp(lo, lo, CTRL, 0xf, 0xf, false);
    int phi = __builtin_amdgcn_update_dpp(hi, hi, CTRL, 0xf, 0xf, false);
    unsigned long long p = ((unsigned long long)(unsigned int)phi << 32) | (unsigned int)plo;
    return (p > k) ? p : k;
}
__device__ __forceinline__ unsigned long long wave_max_u64(unsigned long long k) {
    k = wmax_step<0x111>(k);   // row_shr:1
    k = wmax_step<0x112>(k);   // row_shr:2
    k = wmax_step<0x114>(k);   // row_shr:4
    k = wmax_step<0x118>(k);   // row_shr:8  -> lane15 of each row has row max
    k = wmax_step<0x142>(k);   // row_bcast15
    k = wmax_step<0x143>(k);   // row_bcast31 -> lane63 has wave max
    unsigned int lo = (unsigned int)__builtin_amdgcn_readlane((int)(unsigned int)k, 63);
    unsigned int hi = (unsigned int)__builtin_amdgcn_readlane((int)(unsigned int)(k >> 32), 63);
    return ((unsigned long long)hi << 32) | lo;
}

// ---------------- K0: prep (transposes, bn scales, templates, cnt=0) ----------------
__global__ void k0_prep(const float* __restrict__ w_gh1, const float* __restrict__ w1,
                        const float* __restrict__ w2, const float* __restrict__ w3,
                        const float* __restrict__ gh_g, const float* __restrict__ gh_v,
                        const float* __restrict__ g1, const float* __restrict__ v1,
                        const float* __restrict__ g2, const float* __restrict__ v2,
                        float* __restrict__ ws) {
    int id = blockIdx.x * 256 + threadIdx.x;
    if (id < 65536) {
        int k = id & 255, o = id >> 8;
        ws[W_GH1T + k * 256 + o] = w_gh1[id];
    } else if (id < 131072) {
        int l = id - 65536; int k = l & 255, o = l >> 8;
        ws[W_W1T + k * 256 + o] = w1[l];
    } else if (id < 207872) {
        int l = id - 131072; int k = l & 255, o = l >> 8;
        ws[W_W2T + k * 320 + o] = w2[l];
    } else if (id < 297872) {
        int l = id - 207872; int k = l % 300, o = l / 300;
        ws[W_W3T + k * 320 + o] = w3[l];
    } else if (id < 298172) {
        int i = id - 297872;
        double phi = (sqrt(5.0) - 1.0) / 2.0;
        double zi = (2.0 * (double)i + 1.0) / 300.0 - 1.0;
        double r2 = 1.0 - zi * zi; if (r2 < 0.0) r2 = 0.0;
        double ri = sqrt(r2);
        double th = (6.283185307179586 * (double)i) * phi;
        ws[W_TMPL + i * 3 + 0] = (float)(ri * cos(th));
        ws[W_TMPL + i * 3 + 1] = (float)(ri * sin(th));
        ws[W_TMPL + i * 3 + 2] = (float)zi;
    } else if (id < 298428) {
        int i = id - 298172; ws[W_SGH + i] = gh_g[i] / sqrtf(gh_v[i] + 1e-5f);
    } else if (id < 298684) {
        int i = id - 298428; ws[W_SC1 + i] = g1[i] / sqrtf(v1[i] + 1e-5f);
    } else if (id < 298984) {
        int i = id - 298684; ws[W_SC2 + i] = g2[i] / sqrtf(v2[i] + 1e-5f);
    } else if (id < 298988) {
        ((int*)(ws + W_CNT))[id - 298984] = 0;
    }
}

// ---------------- K1: fused stage A (64-wide n-tile) ----------------
// h = relu(bn(W1 x)); graspable = W2 h + b2; masks. Accumulation order identical
// to the verified round-1 kernel (serial ascending c, bias added last).
// __launch_bounds__(256,2): LDS (64KB) caps at 2 blocks/CU = 2 waves/EU anyway;
// without the explicit min-waves arg the compiler capped VGPRs at 64 and
// spilled the 8x8 accumulator tile to scratch.
__global__ __launch_bounds__(256, 2) void k1_stageA(
    const float* __restrict__ x,       // seed_features (B,256,20000)
    const float* __restrict__ wt,      // gh_w1^T [c][256]
    const float* __restrict__ b1g, const float* __restrict__ scg,
    const float* __restrict__ m1g, const float* __restrict__ be1g,
    const float* __restrict__ w2g, const float* __restrict__ b2g,   // (3,256),(3)
    float* __restrict__ out_grasp, float* __restrict__ out_obj, int* __restrict__ maskw) {
    __shared__ __align__(16) float Xs[256 * 64];   // 64 KB
    int b = blockIdx.y;
    int n0 = blockIdx.x * 64;
    int t = threadIdx.x;
    const float* xb = x + (size_t)b * CC * NN;
    #pragma unroll
    for (int k = 0; k < 16; k++) {
        int id = t + k * 256; int c = id >> 4; int u = id & 15;
        int n = n0 + u * 4;
        float4 v = make_float4(0.f, 0.f, 0.f, 0.f);
        if (n < NN) v = *(const float4*)(xb + (size_t)c * NN + n);
        *(float4*)(Xs + c * 64 + u * 4) = v;
    }
    __syncthreads();
    int og = (t >> 3) * 8;
    int n8 = (t & 7) * 8;
    float acc[8][8] = {};
    #pragma unroll 2
    for (int c = 0; c < 256; c++) {
        float4 wva = *(const float4*)(wt + c * 256 + og);
        float4 wvb = *(const float4*)(wt + c * 256 + og + 4);
        float4 xva = *(const float4*)(Xs + c * 64 + n8);
        float4 xvb = *(const float4*)(Xs + c * 64 + n8 + 4);
        float wr[8] = {wva.x, wva.y, wva.z, wva.w, wvb.x, wvb.y, wvb.z, wvb.w};
        float xr[8] = {xva.x, xva.y, xva.z, xva.w, xvb.x, xvb.y, xvb.z, xvb.w};
        #pragma unroll
        for (int i = 0; i < 8; i++)
            #pragma unroll
            for (int j = 0; j < 8; j++)
                acc[i][j] = fmaf(wr[i], xr[j], acc[i][j]);
    }
    __syncthreads();   // all reads of Xs done; reuse as h-tile
    #pragma unroll
    for (int i = 0; i < 8; i++) {
        int o = og + i;
        float bb = b1g[o], mm = m1g[o], ssv = scg[o], ee = be1g[o];
        float tmp[8];
        #pragma unroll
        for (int j = 0; j < 8; j++) {
            float y = __fadd_rn(acc[i][j], bb);
            y = __fadd_rn(__fmul_rn(__fsub_rn(y, mm), ssv), ee);
            tmp[j] = fmaxf(y, 0.0f);
        }
        *(float4*)(Xs + o * 64 + n8)     = make_float4(tmp[0], tmp[1], tmp[2], tmp[3]);
        *(float4*)(Xs + o * 64 + n8 + 4) = make_float4(tmp[4], tmp[5], tmp[6], tmp[7]);
    }
    __syncthreads();
    if (t < 64) {
        float s0a = 0.0f, s1a = 0.0f, s2a = 0.0f;
        for (int c = 0; c < 256; c++) {
            float xv = Xs[c * 64 + t];
            s0a = fmaf(xv, w2g[c], s0a);
            s1a = fmaf(xv, w2g[256 + c], s1a);
            s2a = fmaf(xv, w2g[512 + c], s2a);
        }
        int n = n0 + t;
        if (n < NN) {
            float s0 = __fadd_rn(s0a, b2g[0]);
            float s1 = __fadd_rn(s1a, b2g[1]);
            float s2 = __fadd_rn(s2a, b2g[2]);
            bool obj = s1 > s0;
            bool gr = obj && (s2 > 0.1f);
            int gn = b * NN + n;
            out_grasp[gn] = s2;
            out_obj[gn] = obj ? 1.0f : 0.0f;
            maskw[gn] = gr ? 1 : 0;
        }
    }
}

// ---------------- K2: compact masked points ----------------
__global__ void k2_compact(const float* __restrict__ sx, const int* __restrict__ maskr,
                           int* __restrict__ cnt, float4* __restrict__ cpk) {
    int id = blockIdx.x * 256 + threadIdx.x;
    if (id >= BB * NN) return;
    int b = id / NN, n = id % NN;
    if (maskr[id]) {
        int pos = atomicAdd(cnt + b, 1);
        const float* p = sx + (size_t)id * 3;
        cpk[b * NN + pos] = make_float4(p[0], p[1], p[2], __uint_as_float((unsigned int)n));
    }
}

// ---------------- K3: FPS — 1 barrier/step, DPP wave reduce, dbuf winner slots ----------------
// __launch_bounds__(512,2): 1 block/CU = 8 waves = 2 waves/EU -> 256-VGPR budget.
// Without the min-waves arg the compiler capped VGPRs at 64 and spilled the
// per-thread point arrays to scratch (98 MB HBM FETCH/dispatch, the r2 bottleneck).
template <int PPT>
__global__ __launch_bounds__(512, 2) void k3_fps(const float4* __restrict__ cpk,
                                                 const int* __restrict__ cnt,
                                                 float* __restrict__ out_inds,
                                                 int* __restrict__ inds_i, int lo, int hi) {
    int b = blockIdx.x;
    int t = threadIdx.x;
    int M = cnt[b];
    int need = (M + 511) >> 9;
    if (!(need > lo && need <= hi)) return;   // exactly one variant proceeds per batch
    __shared__ unsigned long long skey[2][8];
    __shared__ __align__(16) float4 scd[2][8];
    if (M == 0) {
        for (int s = t; s < SS; s += 512) { out_inds[b * SS + s] = 0.0f; inds_i[b * SS + s] = 0; }
        return;
    }
    float px[PPT], py[PPT], pz[PPT], dist[PPT];
    unsigned int pid[PPT];
    int wid = t >> 6, lane = t & 63;
    unsigned long long bkey = 0ull;
    float bx = 0, by = 0, bz = 0;
    #pragma unroll
    for (int j = 0; j < PPT; j++) {
        int p = t + (j << 9);
        if (p < M) {
            float4 v = cpk[b * NN + p];
            px[j] = v.x; py[j] = v.y; pz[j] = v.z;
            pid[j] = __float_as_uint(v.w);
            dist[j] = 1e10f;
            unsigned long long k = (0xFFFFFFFFull << 32) | (unsigned int)(~pid[j]);
            if (k > bkey) { bkey = k; bx = v.x; by = v.y; bz = v.z; }
        } else {
            px[j] = py[j] = pz[j] = 0.0f; dist[j] = 0.0f; pid[j] = 0u;
        }
    }
    // publish initial winner (start = first masked index)
    {
        unsigned long long wkey = wave_max_u64(bkey);
        unsigned long long mb = __ballot(bkey == wkey);
        if (lane == __ffsll((long long)mb) - 1) {
            skey[0][wid] = wkey;
            scd[0][wid] = make_float4(bx, by, bz, 0.0f);
        }
    }
    __syncthreads();
    int buf = 0;
    for (int step = 0; step < SS; step++) {
        // combine the 8 wave slots (broadcast LDS reads, done by every thread)
        unsigned long long wk = skey[buf][0];
        float4 c = scd[buf][0];
        #pragma unroll
        for (int i = 1; i < 8; i++) {
            unsigned long long k2 = skey[buf][i];
            float4 c2 = scd[buf][i];
            if (k2 > wk) { wk = k2; c = c2; }
        }
        unsigned int cid = ~(unsigned int)(wk & 0xFFFFFFFFull);
        if (t == 0) { out_inds[b * SS + step] = (float)cid; inds_i[b * SS + step] = (int)cid; }
        // distance update + per-lane best
        bkey = 0ull; bx = by = bz = 0.0f;
        #pragma unroll
        for (int j = 0; j < PPT; j++) {
            int p = t + (j << 9);
            if (p < M) {
                float dx = __fsub_rn(px[j], c.x);
                float dy = __fsub_rn(py[j], c.y);
                float dz = __fsub_rn(pz[j], c.z);
                float d = __fadd_rn(__fadd_rn(__fmul_rn(dx, dx), __fmul_rn(dy, dy)), __fmul_rn(dz, dz));
                float nd = fminf(dist[j], d);
                dist[j] = nd;
                // nd >= 0 always -> monotone key is just (bits | signbit)
                unsigned long long k = ((unsigned long long)(__float_as_uint(nd) | 0x80000000u) << 32)
                                       | (unsigned int)(~pid[j]);
                if (k > bkey) { bkey = k; bx = px[j]; by = py[j]; bz = pz[j]; }
            }
        }
        unsigned long long wkey = wave_max_u64(bkey);
        unsigned long long mb = __ballot(bkey == wkey);
        if (lane == __ffsll((long long)mb) - 1) {
            skey[buf ^ 1][wid] = wkey;
            scd[buf ^ 1][wid] = make_float4(bx, by, bz, 0.0f);
        }
        __syncthreads();
        buf ^= 1;
    }
}

// ---------------- K4a: feature gather (one thread per output element) ----------------
__global__ void k4_gatherF(const float* __restrict__ sf, const int* __restrict__ inds,
                           float* __restrict__ o_feat) {
    int id = blockIdx.x * 256 + threadIdx.x;   // B*C*S = 1,048,576
    int s = id & (SS - 1);
    int bc = id >> 10;                          // b*C + c
    int b = bc >> 8;
    int idx = inds[(b << 10) | s];
    o_feat[id] = sf[(size_t)bc * NN + idx];
}

// ---------------- K4b: xyz + graspness gather ----------------
__global__ void k4_gatherX(const float* __restrict__ sx, const int* __restrict__ inds,
                           const float* __restrict__ grasp_all,
                           float* __restrict__ o_xyz, float* __restrict__ o_fg) {
    int id = blockIdx.x * 256 + threadIdx.x;   // 4096
    int b = id >> 10;
    int idx = inds[id];
    const float* p = sx + ((size_t)b * NN + idx) * 3;
    o_xyz[id * 3 + 0] = p[0];
    o_xyz[id * 3 + 1] = p[1];
    o_xyz[id * 3 + 2] = p[2];
    o_fg[id] = grasp_all[b * NN + idx];
}

// ---------------- K5: generic conv1x1 GEMM over 1024 pts (+optional bn+relu) ----------------
__global__ __launch_bounds__(256, 2) void k5_gemm(const float* __restrict__ X, const float* __restrict__ WT,
                                                  const float* __restrict__ bias, const float* __restrict__ scale,
                                                  const float* __restrict__ mean, const float* __restrict__ beta,
                                                  float* __restrict__ Y, int O, int Opad, int K, int relu_bn) {
    __shared__ __align__(16) float Xs[64 * 64];
    int b = blockIdx.z;
    int n0 = blockIdx.y * 64;
    int o0 = blockIdx.x * 64;
    int t = threadIdx.x;
    int o4 = o0 + (t & 15) * 4;
    int n4 = (t >> 4) * 4;
    float acc[4][4] = {};
    const float* Xb = X + (size_t)b * K * SS;
    for (int c0 = 0; c0 < K; c0 += 64) {
        #pragma unroll
        for (int k = 0; k < 4; k++) {
            int id = t + k * 256; int cc = id >> 4; int nn4 = (id & 15) * 4;
            int c = c0 + cc;
            float4 v = make_float4(0.f, 0.f, 0.f, 0.f);
            if (c < K) v = *(const float4*)(Xb + (size_t)c * SS + n0 + nn4);
            *(float4*)(Xs + cc * 64 + nn4) = v;
        }
        __syncthreads();
        int kmax = (K - c0 < 64) ? (K - c0) : 64;
        for (int cc = 0; cc < kmax; cc++) {
            float4 wv = *(const float4*)(WT + (size_t)(c0 + cc) * Opad + o4);
            float4 xv = *(const float4*)(Xs + cc * 64 + n4);
            float wr[4] = {wv.x, wv.y, wv.z, wv.w};
            float xr[4] = {xv.x, xv.y, xv.z, xv.w};
            #pragma unroll
            for (int i = 0; i < 4; i++)
                #pragma unroll
                for (int j = 0; j < 4; j++)
                    acc[i][j] = fmaf(wr[i], xr[j], acc[i][j]);
        }
        __syncthreads();
    }
    #pragma unroll
    for (int i = 0; i < 4; i++) {
        int o = o4 + i;
        if (o >= O) continue;
        float bb = bias[o];
        float val[4];
        if (relu_bn) {
            float ssv = scale[o], mm = mean[o], ee = beta[o];
            #pragma unroll
            for (int j = 0; j < 4; j++) {
                float y = __fadd_rn(acc[i][j], bb);
                y = __fadd_rn(__fmul_rn(__fsub_rn(y, mm), ssv), ee);
                val[j] = fmaxf(y, 0.0f);
            }
        } else {
            #pragma unroll
            for (int j = 0; j < 4; j++) val[j] = __fadd_rn(acc[i][j], bb);
        }
        *(float4*)(Y + ((size_t)b * O + o) * SS + n0 + n4) = make_float4(val[0], val[1], val[2], val[3]);
    }
}

// ---------------- K6: view max/argmax (4-way parallel over V) + rotations ----------------
__global__ void k6_view(const float* __restrict__ F3v, const float* __restrict__ tmpl,
                        float* __restrict__ o_ti, float* __restrict__ o_ts,
                        float* __restrict__ o_vx, float* __restrict__ o_vr) {
    __shared__ float sv[4][64];
    __shared__ int si[4][64];
    int blk = blockIdx.x;                 // 64 blocks
    int b = blk >> 4;
    int s0 = (blk & 15) << 6;
    int t = threadIdx.x;
    int sl = t & 63, g = t >> 6;
    const float* f = F3v + (size_t)b * VV * SS + s0 + sl;
    int v0 = g * 75;
    float best = f[(size_t)v0 * SS];
    int bi = v0;
    for (int v = v0 + 1; v < v0 + 75; v++) {
        float x = f[(size_t)v * SS];
        if (x > best) { best = x; bi = v; }   // strict > keeps first max
    }
    sv[g][sl] = best; si[g][sl] = bi;
    __syncthreads();
    if (t < 64) {
        float bv = sv[0][t]; int bix = si[0][t];
        #pragma unroll
        for (int g2 = 1; g2 < 4; g2++) {
            float x = sv[g2][t];
            if (x > bv) { bv = x; bix = si[g2][t]; }   // ties -> earlier group (smaller v)
        }
        int id = (b << 10) + s0 + t;
        o_ti[id] = (float)bix;
        o_ts[id] = bv;
        float tx = tmpl[bix * 3 + 0], ty = tmpl[bix * 3 + 1], tz = tmpl[bix * 3 + 2];
        o_vx[id * 3 + 0] = tx; o_vx[id * 3 + 1] = ty; o_vx[id * 3 + 2] = tz;
        // towards = -vp_xyz
        float ax0 = -tx, ax1 = -ty, ax2 = -tz;
        float ay0 = ty, ay1 = -tx, ay2 = 0.0f;   // (-ax1, ax0, 0)
        float ny = sqrtf(__fadd_rn(__fadd_rn(__fmul_rn(ay0, ay0), __fmul_rn(ay1, ay1)), __fmul_rn(ay2, ay2)));
        if (ny == 0.0f) { ay0 = 0.0f; ay1 = 1.0f; ay2 = 0.0f; }
        float nx = sqrtf(__fadd_rn(__fadd_rn(__fmul_rn(ax0, ax0), __fmul_rn(ax1, ax1)), __fmul_rn(ax2, ax2)));
        ax0 = ax0 / nx; ax1 = ax1 / nx; ax2 = ax2 / nx;
        float ny2 = sqrtf(__fadd_rn(__fadd_rn(__fmul_rn(ay0, ay0), __fmul_rn(ay1, ay1)), __fmul_rn(ay2, ay2)));
        ay0 = ay0 / ny2; ay1 = ay1 / ny2; ay2 = ay2 / ny2;
        float az0 = __fsub_rn(__fmul_rn(ax1, ay2), __fmul_rn(ax2, ay1));
        float az1 = __fsub_rn(__fmul_rn(ax2, ay0), __fmul_rn(ax0, ay2));
        float az2 = __fsub_rn(__fmul_rn(ax0, ay1), __fmul_rn(ax1, ay0));
        float* R = o_vr + (size_t)id * 9;   // columns = (ax, ay, az)
        R[0] = ax0; R[1] = ay0; R[2] = az0;
        R[3] = ax1; R[4] = ay1; R[5] = az1;
        R[6] = ax2; R[7] = ay2; R[8] = az2;
    }
}

// ---------------- K7: transpose f3 (B,300,1024) -> view_score (B,1024,300) ----------------
__global__ void k7_transpose(const float* __restrict__ F3v, float* __restrict__ outp) {
    __shared__ float T[64][65];
    int b = blockIdx.z;
    int s0 = blockIdx.y * 64;
    int v0 = blockIdx.x * 64;
    int t = threadIdx.x;
    int sc = t & 63;
    int g = t >> 6;
    #pragma unroll
    for (int k = 0; k < 16; k++) {
        int vr = g * 16 + k;
        int v = v0 + vr;
        T[vr][sc] = (v < VV) ? F3v[((size_t)b * VV + v) * SS + s0 + sc] : 0.0f;
    }
    __syncthreads();
    #pragma unroll
    for (int k = 0; k < 16; k++) {
        int sr = g * 16 + k;
        int v = v0 + sc;
        if (v < VV)
            outp[((size_t)b * SS + (s0 + sr)) * VV + v] = T[sc][sr];
    }
}

extern "C" void kernel_launch(void* const* d_in, const int* in_sizes, int n_in,
                              void* d_out, int out_size, void* d_ws, size_t ws_size,
                              hipStream_t stream) {
    const float* seed_xyz  = (const float*)d_in[0];
    const float* seed_feat = (const float*)d_in[1];
    const float* gh_w1 = (const float*)d_in[2];
    const float* gh_b1 = (const float*)d_in[3];
    const float* gh_g1 = (const float*)d_in[4];
    const float* gh_be1 = (const float*)d_in[5];
    const float* gh_m1 = (const float*)d_in[6];
    const float* gh_v1 = (const float*)d_in[7];
    const float* gh_w2 = (const float*)d_in[8];
    const float* gh_b2 = (const float*)d_in[9];
    const float* w1 = (const float*)d_in[10];
    const float* b1 = (const float*)d_in[11];
    const float* g1 = (const float*)d_in[12];
    const float* be1 = (const float*)d_in[13];
    const float* m1 = (const float*)d_in[14];
    const float* v1 = (const float*)d_in[15];
    const float* w2 = (const float*)d_in[16];
    const float* b2 = (const float*)d_in[17];
    const float* g2 = (const float*)d_in[18];
    const float* be2 = (const float*)d_in[19];
    const float* m2 = (const float*)d_in[20];
    const float* v2 = (const float*)d_in[21];
    const float* w3 = (const float*)d_in[22];
    const float* b3 = (const float*)d_in[23];

    float* out = (float*)d_out;
    float* ws = (float*)d_ws;
    int* cnt = (int*)(ws + W_CNT);
    float4* cpk = (float4*)(ws + W_CPK);
    int* inds_i = (int*)(ws + W_INDS);
    int* maskw = (int*)(ws + W_MASK);

    // K0: prep
    k0_prep<<<dim3((298988 + 255) / 256), dim3(256), 0, stream>>>(
        gh_w1, w1, w2, w3, gh_g1, gh_v1, g1, v1, g2, v2, ws);

    // K1: fused stage A (64-wide tiles)
    k1_stageA<<<dim3((NN + 63) / 64, BB), dim3(256), 0, stream>>>(
        seed_feat, ws + W_GH1T, gh_b1, ws + W_SGH, gh_m1, gh_be1, gh_w2, gh_b2,
        out + O_GRASP, out + O_OBJ, maskw);

    // K2: compaction
    k2_compact<<<dim3((BB * NN + 255) / 256), dim3(256), 0, stream>>>(seed_xyz, maskw, cnt, cpk);

    // K3: FPS (three self-selecting register-capacity variants)
    k3_fps<13><<<dim3(BB), dim3(512), 0, stream>>>(cpk, cnt, out + O_INDS, inds_i, -1, 13);
    k3_fps<26><<<dim3(BB), dim3(512), 0, stream>>>(cpk, cnt, out + O_INDS, inds_i, 13, 26);
    k3_fps<40><<<dim3(BB), dim3(512), 0, stream>>>(cpk, cnt, out + O_INDS, inds_i, 26, 40);

    // K4: gathers
    k4_gatherF<<<dim3(BB * CC * SS / 256), dim3(256), 0, stream>>>(seed_feat, inds_i, out + O_GFEAT);
    k4_gatherX<<<dim3(BB * SS / 256), dim3(256), 0, stream>>>(
        seed_xyz, inds_i, out + O_GRASP, out + O_GXYZ, out + O_FPG);

    // K5: stage C MLP (three conv1x1 layers)
    k5_gemm<<<dim3(4, 16, BB), dim3(256), 0, stream>>>(
        out + O_GFEAT, ws + W_W1T, b1, ws + W_SC1, m1, be1, ws + W_F1, 256, 256, 256, 1);
    k5_gemm<<<dim3(5, 16, BB), dim3(256), 0, stream>>>(
        ws + W_F1, ws + W_W2T, b2, ws + W_SC2, m2, be2, ws + W_F2, 300, 320, 256, 1);
    k5_gemm<<<dim3(5, 16, BB), dim3(256), 0, stream>>>(
        ws + W_F2, ws + W_W3T, b3, b3, b3, b3, ws + W_F3, 300, 320, 300, 0);

    // K6: view argmax + rotations
    k6_view<<<dim3(64), dim3(256), 0, stream>>>(
        ws + W_F3, ws + W_TMPL, out + O_TVI, out + O_TVS, out + O_VPX, out + O_VPR);

    // K7: view_score transpose
    k7_transpose<<<dim3(5, 16, BB), dim3(256), 0, stream>>>(ws + W_F3, out + O_VIEW);
}

// Round 4
// 1656.587 us; speedup vs baseline: 1.1316x; 1.0041x over previous
//
#include <hip/hip_runtime.h>
#include <math.h>

// ---------------- problem constants ----------------
#define BB 4
#define NN 20000
#define CC 256
#define VV 300
#define SS 1024

// output float offsets (concatenated flat, all read back as float32)
#define O_GRASP   0          // (4,20000)
#define O_OBJ     80000      // (4,20000)
#define O_GXYZ    160000     // (4,1024,3)
#define O_INDS    172288     // (4,1024)
#define O_GFEAT   176384     // (4,256,1024)
#define O_FPG     1224960    // (4,1024)
#define O_VIEW    1229056    // (4,1024,300)
#define O_TVI     2457856    // (4,1024)
#define O_TVS     2461952    // (4,1024)
#define O_VPX     2466048    // (4,1024,3)
#define O_VPR     2478336    // (4,1024,3,3)

// ws float offsets
#define W_GH1T    0          // [256 c][256 o]
#define W_W1T     65536      // [256 c][256 o]
#define W_W2T     131072     // [256 c][320 o-pad] (O=300)
#define W_W3T     212992     // [300 c][320 o-pad] (O=300)
#define W_TMPL    308992     // 300*3
#define W_SGH     309892     // 256
#define W_SC1     310148     // 256
#define W_SC2     310404     // 300
#define W_CNT     310704     // 4 ints (pad to 310720)
#define W_CPK     310720     // 4*20000 float4 (x,y,z,idx-bits)
#define W_INDS    630720     // 4*1024 int
#define W_MASK    634816     // 4*20000 int
#define W_F1      714816     // 4*256*1024
#define W_F2      1763392    // 4*300*1024
#define W_F3      2992192    // 4*300*1024  (end 4220992 floats = 16.9 MB)

// FMA a 4-vector accumulator: A += W * X (componentwise), exact fmaf per element.
#define FMA4(A, W, X) do { \
    A.x = fmaf((W), (X).x, A.x); \
    A.y = fmaf((W), (X).y, A.y); \
    A.z = fmaf((W), (X).z, A.z); \
    A.w = fmaf((W), (X).w, A.w); } while (0)

__device__ __forceinline__ float4 bnrelu4(float4 a, float bb, float mm, float ssv, float ee) {
    float4 r;
    r.x = fmaxf(__fadd_rn(__fmul_rn(__fsub_rn(__fadd_rn(a.x, bb), mm), ssv), ee), 0.0f);
    r.y = fmaxf(__fadd_rn(__fmul_rn(__fsub_rn(__fadd_rn(a.y, bb), mm), ssv), ee), 0.0f);
    r.z = fmaxf(__fadd_rn(__fmul_rn(__fsub_rn(__fadd_rn(a.z, bb), mm), ssv), ee), 0.0f);
    r.w = fmaxf(__fadd_rn(__fmul_rn(__fsub_rn(__fadd_rn(a.w, bb), mm), ssv), ee), 0.0f);
    return r;
}

// ---- DPP-based wave64 max reduction on u64 keys (result broadcast to all lanes) ----
template <int CTRL>
__device__ __forceinline__ unsigned long long wmax_step(unsigned long long k) {
    int lo = (int)(unsigned int)k;
    int hi = (int)(unsigned int)(k >> 32);
    int plo = __builtin_amdgcn_update_dpp(lo, lo, CTRL, 0xf, 0xf, false);
    int phi = __builtin_amdgcn_update_dpp(hi, hi, CTRL, 0xf, 0xf, false);
    unsigned long long p = ((unsigned long long)(unsigned int)phi << 32) | (unsigned int)plo;
    return (p > k) ? p : k;
}
__device__ __forceinline__ unsigned long long wave_max_u64(unsigned long long k) {
    k = wmax_step<0x111>(k);   // row_shr:1
    k = wmax_step<0x112>(k);   // row_shr:2
    k = wmax_step<0x114>(k);   // row_shr:4
    k = wmax_step<0x118>(k);   // row_shr:8  -> lane15 of each row has row max
    k = wmax_step<0x142>(k);   // row_bcast15
    k = wmax_step<0x143>(k);   // row_bcast31 -> lane63 has wave max
    unsigned int lo = (unsigned int)__builtin_amdgcn_readlane((int)(unsigned int)k, 63);
    unsigned int hi = (unsigned int)__builtin_amdgcn_readlane((int)(unsigned int)(k >> 32), 63);
    return ((unsigned long long)hi << 32) | lo;
}

// ---- FPS per-thread point storage: recursive struct of scalars.
// Every access is a constant-offset struct member -> SROA promotion to VGPRs is
// structurally guaranteed (no array allocas, no dependence on unroll ordering).
// Round-3 evidence: array version stayed in scratch (VGPR=64, 98 MB HBM/dispatch).
template <int N> struct Pts {
    Pts<N - 1> rest;
    float px, py, pz, dist;
    unsigned int pid;
};
template <> struct Pts<0> {};

template <int N>
__device__ __forceinline__ void pts_load(Pts<N>& P, const float4* __restrict__ base,
                                         int t, int M,
                                         unsigned long long& bkey, float& bx, float& by, float& bz) {
    if constexpr (N > 0) {
        pts_load(P.rest, base, t, M, bkey, bx, by, bz);   // ascending J order
        constexpr int J = N - 1;
        int p = t + (J << 9);
        if (p < M) {
            float4 v = base[p];
            P.px = v.x; P.py = v.y; P.pz = v.z;
            P.pid = __float_as_uint(v.w);
            P.dist = 1e10f;
            unsigned long long k = (0xFFFFFFFFull << 32) | (unsigned int)(~P.pid);
            if (k > bkey) { bkey = k; bx = v.x; by = v.y; bz = v.z; }
        } else {
            P.px = P.py = P.pz = 0.0f; P.dist = 0.0f; P.pid = 0u;
        }
    }
}

template <int N>
__device__ __forceinline__ void pts_upd(Pts<N>& P, int t, int M,
                                        float cx, float cy, float cz,
                                        unsigned long long& bkey, float& bx, float& by, float& bz) {
    if constexpr (N > 0) {
        pts_upd(P.rest, t, M, cx, cy, cz, bkey, bx, by, bz);
        constexpr int J = N - 1;
        int p = t + (J << 9);
        if (p < M) {
            float dx = __fsub_rn(P.px, cx);
            float dy = __fsub_rn(P.py, cy);
            float dz = __fsub_rn(P.pz, cz);
            float d = __fadd_rn(__fadd_rn(__fmul_rn(dx, dx), __fmul_rn(dy, dy)), __fmul_rn(dz, dz));
            float nd = fminf(P.dist, d);
            P.dist = nd;
            // nd >= 0 always -> monotone key is just (bits | signbit)
            unsigned long long k = ((unsigned long long)(__float_as_uint(nd) | 0x80000000u) << 32)
                                   | (unsigned int)(~P.pid);
            if (k > bkey) { bkey = k; bx = P.px; by = P.py; bz = P.pz; }
        }
    }
}

// ---------------- K0: prep (transposes, bn scales, templates, cnt=0) ----------------
__global__ void k0_prep(const float* __restrict__ w_gh1, const float* __restrict__ w1,
                        const float* __restrict__ w2, const float* __restrict__ w3,
                        const float* __restrict__ gh_g, const float* __restrict__ gh_v,
                        const float* __restrict__ g1, const float* __restrict__ v1,
                        const float* __restrict__ g2, const float* __restrict__ v2,
                        float* __restrict__ ws) {
    int id = blockIdx.x * 256 + threadIdx.x;
    if (id < 65536) {
        int k = id & 255, o = id >> 8;
        ws[W_GH1T + k * 256 + o] = w_gh1[id];
    } else if (id < 131072) {
        int l = id - 65536; int k = l & 255, o = l >> 8;
        ws[W_W1T + k * 256 + o] = w1[l];
    } else if (id < 207872) {
        int l = id - 131072; int k = l & 255, o = l >> 8;
        ws[W_W2T + k * 320 + o] = w2[l];
    } else if (id < 297872) {
        int l = id - 207872; int k = l % 300, o = l / 300;
        ws[W_W3T + k * 320 + o] = w3[l];
    } else if (id < 298172) {
        int i = id - 297872;
        double phi = (sqrt(5.0) - 1.0) / 2.0;
        double zi = (2.0 * (double)i + 1.0) / 300.0 - 1.0;
        double r2 = 1.0 - zi * zi; if (r2 < 0.0) r2 = 0.0;
        double ri = sqrt(r2);
        double th = (6.283185307179586 * (double)i) * phi;
        ws[W_TMPL + i * 3 + 0] = (float)(ri * cos(th));
        ws[W_TMPL + i * 3 + 1] = (float)(ri * sin(th));
        ws[W_TMPL + i * 3 + 2] = (float)zi;
    } else if (id < 298428) {
        int i = id - 298172; ws[W_SGH + i] = gh_g[i] / sqrtf(gh_v[i] + 1e-5f);
    } else if (id < 298684) {
        int i = id - 298428; ws[W_SC1 + i] = g1[i] / sqrtf(v1[i] + 1e-5f);
    } else if (id < 298984) {
        int i = id - 298684; ws[W_SC2 + i] = g2[i] / sqrtf(v2[i] + 1e-5f);
    } else if (id < 298988) {
        ((int*)(ws + W_CNT))[id - 298984] = 0;
    }
}

// ---------------- K1: fused stage A (64-wide n-tile, named float4 accumulators) ----------------
// h = relu(bn(W1 x)); graspable = W2 h + b2; masks. Accumulation order identical
// to the verified round-1 kernel (serial ascending c, bias added last).
__global__ __launch_bounds__(256, 2) void k1_stageA(
    const float* __restrict__ x,       // seed_features (B,256,20000)
    const float* __restrict__ wt,      // gh_w1^T [c][256]
    const float* __restrict__ b1g, const float* __restrict__ scg,
    const float* __restrict__ m1g, const float* __restrict__ be1g,
    const float* __restrict__ w2g, const float* __restrict__ b2g,   // (3,256),(3)
    float* __restrict__ out_grasp, float* __restrict__ out_obj, int* __restrict__ maskw) {
    __shared__ __align__(16) float Xs[256 * 64];   // 64 KB
    int b = blockIdx.y;
    int n0 = blockIdx.x * 64;
    int t = threadIdx.x;
    const float* xb = x + (size_t)b * CC * NN;
    #pragma unroll
    for (int k = 0; k < 16; k++) {
        int id = t + k * 256; int c = id >> 4; int u = id & 15;
        int n = n0 + u * 4;
        float4 v = make_float4(0.f, 0.f, 0.f, 0.f);
        if (n < NN) v = *(const float4*)(xb + (size_t)c * NN + n);
        *(float4*)(Xs + c * 64 + u * 4) = v;
    }
    __syncthreads();
    int og = (t >> 3) * 8;
    int n8 = (t & 7) * 8;
    float4 a0l = {0,0,0,0}, a0h = {0,0,0,0}, a1l = {0,0,0,0}, a1h = {0,0,0,0};
    float4 a2l = {0,0,0,0}, a2h = {0,0,0,0}, a3l = {0,0,0,0}, a3h = {0,0,0,0};
    float4 a4l = {0,0,0,0}, a4h = {0,0,0,0}, a5l = {0,0,0,0}, a5h = {0,0,0,0};
    float4 a6l = {0,0,0,0}, a6h = {0,0,0,0}, a7l = {0,0,0,0}, a7h = {0,0,0,0};
    #pragma unroll 2
    for (int c = 0; c < 256; c++) {
        float4 wva = *(const float4*)(wt + c * 256 + og);
        float4 wvb = *(const float4*)(wt + c * 256 + og + 4);
        float4 xva = *(const float4*)(Xs + c * 64 + n8);
        float4 xvb = *(const float4*)(Xs + c * 64 + n8 + 4);
        FMA4(a0l, wva.x, xva); FMA4(a0h, wva.x, xvb);
        FMA4(a1l, wva.y, xva); FMA4(a1h, wva.y, xvb);
        FMA4(a2l, wva.z, xva); FMA4(a2h, wva.z, xvb);
        FMA4(a3l, wva.w, xva); FMA4(a3h, wva.w, xvb);
        FMA4(a4l, wvb.x, xva); FMA4(a4h, wvb.x, xvb);
        FMA4(a5l, wvb.y, xva); FMA4(a5h, wvb.y, xvb);
        FMA4(a6l, wvb.z, xva); FMA4(a6h, wvb.z, xvb);
        FMA4(a7l, wvb.w, xva); FMA4(a7h, wvb.w, xvb);
    }
    __syncthreads();   // all reads of Xs done; reuse as h-tile
#define K1_EPI(I) { int o = og + I; \
    float bb = b1g[o], mm = m1g[o], ssv = scg[o], ee = be1g[o]; \
    *(float4*)(Xs + o * 64 + n8)     = bnrelu4(a##I##l, bb, mm, ssv, ee); \
    *(float4*)(Xs + o * 64 + n8 + 4) = bnrelu4(a##I##h, bb, mm, ssv, ee); }
    K1_EPI(0) K1_EPI(1) K1_EPI(2) K1_EPI(3)
    K1_EPI(4) K1_EPI(5) K1_EPI(6) K1_EPI(7)
#undef K1_EPI
    __syncthreads();
    if (t < 64) {
        float s0a = 0.0f, s1a = 0.0f, s2a = 0.0f;
        for (int c = 0; c < 256; c++) {
            float xv = Xs[c * 64 + t];
            s0a = fmaf(xv, w2g[c], s0a);
            s1a = fmaf(xv, w2g[256 + c], s1a);
            s2a = fmaf(xv, w2g[512 + c], s2a);
        }
        int n = n0 + t;
        if (n < NN) {
            float s0 = __fadd_rn(s0a, b2g[0]);
            float s1 = __fadd_rn(s1a, b2g[1]);
            float s2 = __fadd_rn(s2a, b2g[2]);
            bool obj = s1 > s0;
            bool gr = obj && (s2 > 0.1f);
            int gn = b * NN + n;
            out_grasp[gn] = s2;
            out_obj[gn] = obj ? 1.0f : 0.0f;
            maskw[gn] = gr ? 1 : 0;
        }
    }
}

// ---------------- K2: compact masked points ----------------
__global__ void k2_compact(const float* __restrict__ sx, const int* __restrict__ maskr,
                           int* __restrict__ cnt, float4* __restrict__ cpk) {
    int id = blockIdx.x * 256 + threadIdx.x;
    if (id >= BB * NN) return;
    int b = id / NN, n = id % NN;
    if (maskr[id]) {
        int pos = atomicAdd(cnt + b, 1);
        const float* p = sx + (size_t)id * 3;
        cpk[b * NN + pos] = make_float4(p[0], p[1], p[2], __uint_as_float((unsigned int)n));
    }
}

// ---------------- K3: FPS — 1 barrier/step, DPP wave reduce, dbuf winner slots ----------------
template <int PPT>
__global__ __launch_bounds__(512, 2) void k3_fps(const float4* __restrict__ cpk,
                                                 const int* __restrict__ cnt,
                                                 float* __restrict__ out_inds,
                                                 int* __restrict__ inds_i, int lo, int hi) {
    int b = blockIdx.x;
    int t = threadIdx.x;
    int M = cnt[b];
    int need = (M + 511) >> 9;
    if (!(need > lo && need <= hi)) return;   // exactly one variant proceeds per batch
    __shared__ unsigned long long skey[2][8];
    __shared__ __align__(16) float4 scd[2][8];
    if (M == 0) {
        for (int s = t; s < SS; s += 512) { out_inds[b * SS + s] = 0.0f; inds_i[b * SS + s] = 0; }
        return;
    }
    Pts<PPT> P;
    int wid = t >> 6, lane = t & 63;
    unsigned long long bkey = 0ull;
    float bx = 0, by = 0, bz = 0;
    pts_load(P, cpk + b * NN, t, M, bkey, bx, by, bz);
    // publish initial winner (start = first masked index)
    {
        unsigned long long wkey = wave_max_u64(bkey);
        unsigned long long mb = __ballot(bkey == wkey);
        if (lane == __ffsll((long long)mb) - 1) {
            skey[0][wid] = wkey;
            scd[0][wid] = make_float4(bx, by, bz, 0.0f);
        }
    }
    __syncthreads();
    int buf = 0;
    for (int step = 0; step < SS; step++) {
        // combine the 8 wave slots (broadcast LDS reads, done by every thread)
        unsigned long long wk = skey[buf][0];
        float4 c = scd[buf][0];
        #pragma unroll
        for (int i = 1; i < 8; i++) {
            unsigned long long k2 = skey[buf][i];
            float4 c2 = scd[buf][i];
            if (k2 > wk) { wk = k2; c = c2; }
        }
        unsigned int cid = ~(unsigned int)(wk & 0xFFFFFFFFull);
        if (t == 0) { out_inds[b * SS + step] = (float)cid; inds_i[b * SS + step] = (int)cid; }
        // distance update + per-lane best
        bkey = 0ull; bx = by = bz = 0.0f;
        pts_upd(P, t, M, c.x, c.y, c.z, bkey, bx, by, bz);
        unsigned long long wkey = wave_max_u64(bkey);
        unsigned long long mb = __ballot(bkey == wkey);
        if (lane == __ffsll((long long)mb) - 1) {
            skey[buf ^ 1][wid] = wkey;
            scd[buf ^ 1][wid] = make_float4(bx, by, bz, 0.0f);
        }
        __syncthreads();
        buf ^= 1;
    }
}

// ---------------- K4a: feature gather (one thread per output element) ----------------
__global__ void k4_gatherF(const float* __restrict__ sf, const int* __restrict__ inds,
                           float* __restrict__ o_feat) {
    int id = blockIdx.x * 256 + threadIdx.x;   // B*C*S = 1,048,576
    int s = id & (SS - 1);
    int bc = id >> 10;                          // b*C + c
    int b = bc >> 8;
    int idx = inds[(b << 10) | s];
    o_feat[id] = sf[(size_t)bc * NN + idx];
}

// ---------------- K4b: xyz + graspness gather ----------------
__global__ void k4_gatherX(const float* __restrict__ sx, const int* __restrict__ inds,
                           const float* __restrict__ grasp_all,
                           float* __restrict__ o_xyz, float* __restrict__ o_fg) {
    int id = blockIdx.x * 256 + threadIdx.x;   // 4096
    int b = id >> 10;
    int idx = inds[id];
    const float* p = sx + ((size_t)b * NN + idx) * 3;
    o_xyz[id * 3 + 0] = p[0];
    o_xyz[id * 3 + 1] = p[1];
    o_xyz[id * 3 + 2] = p[2];
    o_fg[id] = grasp_all[b * NN + idx];
}

// ---------------- K5: generic conv1x1 GEMM over 1024 pts (+optional bn+relu) ----------------
__global__ __launch_bounds__(256, 2) void k5_gemm(const float* __restrict__ X, const float* __restrict__ WT,
                                                  const float* __restrict__ bias, const float* __restrict__ scale,
                                                  const float* __restrict__ mean, const float* __restrict__ beta,
                                                  float* __restrict__ Y, int O, int Opad, int K, int relu_bn) {
    __shared__ __align__(16) float Xs[64 * 64];
    int b = blockIdx.z;
    int n0 = blockIdx.y * 64;
    int o0 = blockIdx.x * 64;
    int t = threadIdx.x;
    int o4 = o0 + (t & 15) * 4;
    int n4 = (t >> 4) * 4;
    float4 ac0 = {0,0,0,0}, ac1 = {0,0,0,0}, ac2 = {0,0,0,0}, ac3 = {0,0,0,0};
    const float* Xb = X + (size_t)b * K * SS;
    for (int c0 = 0; c0 < K; c0 += 64) {
        #pragma unroll
        for (int k = 0; k < 4; k++) {
            int id = t + k * 256; int cc = id >> 4; int nn4 = (id & 15) * 4;
            int c = c0 + cc;
            float4 v = make_float4(0.f, 0.f, 0.f, 0.f);
            if (c < K) v = *(const float4*)(Xb + (size_t)c * SS + n0 + nn4);
            *(float4*)(Xs + cc * 64 + nn4) = v;
        }
        __syncthreads();
        int kmax = (K - c0 < 64) ? (K - c0) : 64;
        for (int cc = 0; cc < kmax; cc++) {
            float4 wv = *(const float4*)(WT + (size_t)(c0 + cc) * Opad + o4);
            float4 xv = *(const float4*)(Xs + cc * 64 + n4);
            FMA4(ac0, wv.x, xv);
            FMA4(ac1, wv.y, xv);
            FMA4(ac2, wv.z, xv);
            FMA4(ac3, wv.w, xv);
        }
        __syncthreads();
    }
#define K5_EPI(I) { int o = o4 + I; if (o < O) { \
    float bb = bias[o]; float4 v; \
    if (relu_bn) { v = bnrelu4(ac##I, bb, mean[o], scale[o], beta[o]); } \
    else { v.x = __fadd_rn(ac##I.x, bb); v.y = __fadd_rn(ac##I.y, bb); \
           v.z = __fadd_rn(ac##I.z, bb); v.w = __fadd_rn(ac##I.w, bb); } \
    *(float4*)(Y + ((size_t)b * O + o) * SS + n0 + n4) = v; } }
    K5_EPI(0) K5_EPI(1) K5_EPI(2) K5_EPI(3)
#undef K5_EPI
}

// ---------------- K6: view max/argmax (4-way parallel over V) + rotations ----------------
__global__ void k6_view(const float* __restrict__ F3v, const float* __restrict__ tmpl,
                        float* __restrict__ o_ti, float* __restrict__ o_ts,
                        float* __restrict__ o_vx, float* __restrict__ o_vr) {
    __shared__ float sv[4][64];
    __shared__ int si[4][64];
    int blk = blockIdx.x;                 // 64 blocks
    int b = blk >> 4;
    int s0 = (blk & 15) << 6;
    int t = threadIdx.x;
    int sl = t & 63, g = t >> 6;
    const float* f = F3v + (size_t)b * VV * SS + s0 + sl;
    int v0 = g * 75;
    float best = f[(size_t)v0 * SS];
    int bi = v0;
    for (int v = v0 + 1; v < v0 + 75; v++) {
        float x = f[(size_t)v * SS];
        if (x > best) { best = x; bi = v; }   // strict > keeps first max
    }
    sv[g][sl] = best; si[g][sl] = bi;
    __syncthreads();
    if (t < 64) {
        float bv = sv[0][t]; int bix = si[0][t];
        #pragma unroll
        for (int g2 = 1; g2 < 4; g2++) {
            float x = sv[g2][t];
            if (x > bv) { bv = x; bix = si[g2][t]; }   // ties -> earlier group (smaller v)
        }
        int id = (b << 10) + s0 + t;
        o_ti[id] = (float)bix;
        o_ts[id] = bv;
        float tx = tmpl[bix * 3 + 0], ty = tmpl[bix * 3 + 1], tz = tmpl[bix * 3 + 2];
        o_vx[id * 3 + 0] = tx; o_vx[id * 3 + 1] = ty; o_vx[id * 3 + 2] = tz;
        // towards = -vp_xyz
        float ax0 = -tx, ax1 = -ty, ax2 = -tz;
        float ay0 = ty, ay1 = -tx, ay2 = 0.0f;   // (-ax1, ax0, 0)
        float ny = sqrtf(__fadd_rn(__fadd_rn(__fmul_rn(ay0, ay0), __fmul_rn(ay1, ay1)), __fmul_rn(ay2, ay2)));
        if (ny == 0.0f) { ay0 = 0.0f; ay1 = 1.0f; ay2 = 0.0f; }
        float nx = sqrtf(__fadd_rn(__fadd_rn(__fmul_rn(ax0, ax0), __fmul_rn(ax1, ax1)), __fmul_rn(ax2, ax2)));
        ax0 = ax0 / nx; ax1 = ax1 / nx; ax2 = ax2 / nx;
        float ny2 = sqrtf(__fadd_rn(__fadd_rn(__fmul_rn(ay0, ay0), __fmul_rn(ay1, ay1)), __fmul_rn(ay2, ay2)));
        ay0 = ay0 / ny2; ay1 = ay1 / ny2; ay2 = ay2 / ny2;
        float az0 = __fsub_rn(__fmul_rn(ax1, ay2), __fmul_rn(ax2, ay1));
        float az1 = __fsub_rn(__fmul_rn(ax2, ay0), __fmul_rn(ax0, ay2));
        float az2 = __fsub_rn(__fmul_rn(ax0, ay1), __fmul_rn(ax1, ay0));
        float* R = o_vr + (size_t)id * 9;   // columns = (ax, ay, az)
        R[0] = ax0; R[1] = ay0; R[2] = az0;
        R[3] = ax1; R[4] = ay1; R[5] = az1;
        R[6] = ax2; R[7] = ay2; R[8] = az2;
    }
}

// ---------------- K7: transpose f3 (B,300,1024) -> view_score (B,1024,300) ----------------
__global__ void k7_transpose(const float* __restrict__ F3v, float* __restrict__ outp) {
    __shared__ float T[64][65];
    int b = blockIdx.z;
    int s0 = blockIdx.y * 64;
    int v0 = blockIdx.x * 64;
    int t = threadIdx.x;
    int sc = t & 63;
    int g = t >> 6;
    #pragma unroll
    for (int k = 0; k < 16; k++) {
        int vr = g * 16 + k;
        int v = v0 + vr;
        T[vr][sc] = (v < VV) ? F3v[((size_t)b * VV + v) * SS + s0 + sc] : 0.0f;
    }
    __syncthreads();
    #pragma unroll
    for (int k = 0; k < 16; k++) {
        int sr = g * 16 + k;
        int v = v0 + sc;
        if (v < VV)
            outp[((size_t)b * SS + (s0 + sr)) * VV + v] = T[sc][sr];
    }
}

extern "C" void kernel_launch(void* const* d_in, const int* in_sizes, int n_in,
                              void* d_out, int out_size, void* d_ws, size_t ws_size,
                              hipStream_t stream) {
    const float* seed_xyz  = (const float*)d_in[0];
    const float* seed_feat = (const float*)d_in[1];
    const float* gh_w1 = (const float*)d_in[2];
    const float* gh_b1 = (const float*)d_in[3];
    const float* gh_g1 = (const float*)d_in[4];
    const float* gh_be1 = (const float*)d_in[5];
    const float* gh_m1 = (const float*)d_in[6];
    const float* gh_v1 = (const float*)d_in[7];
    const float* gh_w2 = (const float*)d_in[8];
    const float* gh_b2 = (const float*)d_in[9];
    const float* w1 = (const float*)d_in[10];
    const float* b1 = (const float*)d_in[11];
    const float* g1 = (const float*)d_in[12];
    const float* be1 = (const float*)d_in[13];
    const float* m1 = (const float*)d_in[14];
    const float* v1 = (const float*)d_in[15];
    const float* w2 = (const float*)d_in[16];
    const float* b2 = (const float*)d_in[17];
    const float* g2 = (const float*)d_in[18];
    const float* be2 = (const float*)d_in[19];
    const float* m2 = (const float*)d_in[20];
    const float* v2 = (const float*)d_in[21];
    const float* w3 = (const float*)d_in[22];
    const float* b3 = (const float*)d_in[23];

    float* out = (float*)d_out;
    float* ws = (float*)d_ws;
    int* cnt = (int*)(ws + W_CNT);
    float4* cpk = (float4*)(ws + W_CPK);
    int* inds_i = (int*)(ws + W_INDS);
    int* maskw = (int*)(ws + W_MASK);

    // K0: prep
    k0_prep<<<dim3((298988 + 255) / 256), dim3(256), 0, stream>>>(
        gh_w1, w1, w2, w3, gh_g1, gh_v1, g1, v1, g2, v2, ws);

    // K1: fused stage A (64-wide tiles)
    k1_stageA<<<dim3((NN + 63) / 64, BB), dim3(256), 0, stream>>>(
        seed_feat, ws + W_GH1T, gh_b1, ws + W_SGH, gh_m1, gh_be1, gh_w2, gh_b2,
        out + O_GRASP, out + O_OBJ, maskw);

    // K2: compaction
    k2_compact<<<dim3((BB * NN + 255) / 256), dim3(256), 0, stream>>>(seed_xyz, maskw, cnt, cpk);

    // K3: FPS (three self-selecting register-capacity variants)
    k3_fps<13><<<dim3(BB), dim3(512), 0, stream>>>(cpk, cnt, out + O_INDS, inds_i, -1, 13);
    k3_fps<26><<<dim3(BB), dim3(512), 0, stream>>>(cpk, cnt, out + O_INDS, inds_i, 13, 26);
    k3_fps<40><<<dim3(BB), dim3(512), 0, stream>>>(cpk, cnt, out + O_INDS, inds_i, 26, 40);

    // K4: gathers
    k4_gatherF<<<dim3(BB * CC * SS / 256), dim3(256), 0, stream>>>(seed_feat, inds_i, out + O_GFEAT);
    k4_gatherX<<<dim3(BB * SS / 256), dim3(256), 0, stream>>>(
        seed_xyz, inds_i, out + O_GRASP, out + O_GXYZ, out + O_FPG);

    // K5: stage C MLP (three conv1x1 layers)
    k5_gemm<<<dim3(4, 16, BB), dim3(256), 0, stream>>>(
        out + O_GFEAT, ws + W_W1T, b1, ws + W_SC1, m1, be1, ws + W_F1, 256, 256, 256, 1);
    k5_gemm<<<dim3(5, 16, BB), dim3(256), 0, stream>>>(
        ws + W_F1, ws + W_W2T, b2, ws + W_SC2, m2, be2, ws + W_F2, 300, 320, 256, 1);
    k5_gemm<<<dim3(5, 16, BB), dim3(256), 0, stream>>>(
        ws + W_F2, ws + W_W3T, b3, b3, b3, b3, ws + W_F3, 300, 320, 300, 0);

    // K6: view argmax + rotations
    k6_view<<<dim3(64), dim3(256), 0, stream>>>(
        ws + W_F3, ws + W_TMPL, out + O_TVI, out + O_TVS, out + O_VPX, out + O_VPR);

    // K7: view_score transpose
    k7_transpose<<<dim3(5, 16, BB), dim3(256), 0, stream>>>(ws + W_F3, out + O_VIEW);
}

// Round 5
// 1487.628 us; speedup vs baseline: 1.2601x; 1.1136x over previous
//
#include <hip/hip_runtime.h>
#include <math.h>

// ---------------- problem constants ----------------
#define BB 4
#define NN 20000
#define CC 256
#define VV 300
#define SS 1024

// output float offsets (concatenated flat, all read back as float32)
#define O_GRASP   0          // (4,20000)
#define O_OBJ     80000      // (4,20000)
#define O_GXYZ    160000     // (4,1024,3)
#define O_INDS    172288     // (4,1024)
#define O_GFEAT   176384     // (4,256,1024)
#define O_FPG     1224960    // (4,1024)
#define O_VIEW    1229056    // (4,1024,300)
#define O_TVI     2457856    // (4,1024)
#define O_TVS     2461952    // (4,1024)
#define O_VPX     2466048    // (4,1024,3)
#define O_VPR     2478336    // (4,1024,3,3)

// ws float offsets
#define W_GH1T    0          // [256 c][256 o]
#define W_W1T     65536      // [256 c][256 o]
#define W_W2T     131072     // [256 c][320 o-pad] (O=300)
#define W_W3T     212992     // [300 c][320 o-pad] (O=300)
#define W_TMPL    308992     // 300*3
#define W_SGH     309892     // 256
#define W_SC1     310148     // 256
#define W_SC2     310404     // 300
#define W_CNT     310704     // 4 ints (pad to 310720)
#define W_CPK     310720     // 4*20000 float4 (x,y,z,idx-bits)
#define W_INDS    630720     // 4*1024 int
#define W_MASK    634816     // 4*20000 int
#define W_F1      714816     // 4*256*1024
#define W_F2      1763392    // 4*300*1024
#define W_F3      2992192    // 4*300*1024  (end 4220992 floats = 16.9 MB)

// FMA a 4-vector accumulator: A += W * X (componentwise), exact fmaf per element.
#define FMA4(A, W, X) do { \
    A.x = fmaf((W), (X).x, A.x); \
    A.y = fmaf((W), (X).y, A.y); \
    A.z = fmaf((W), (X).z, A.z); \
    A.w = fmaf((W), (X).w, A.w); } while (0)

__device__ __forceinline__ float4 bnrelu4(float4 a, float bb, float mm, float ssv, float ee) {
    float4 r;
    r.x = fmaxf(__fadd_rn(__fmul_rn(__fsub_rn(__fadd_rn(a.x, bb), mm), ssv), ee), 0.0f);
    r.y = fmaxf(__fadd_rn(__fmul_rn(__fsub_rn(__fadd_rn(a.y, bb), mm), ssv), ee), 0.0f);
    r.z = fmaxf(__fadd_rn(__fmul_rn(__fsub_rn(__fadd_rn(a.z, bb), mm), ssv), ee), 0.0f);
    r.w = fmaxf(__fadd_rn(__fmul_rn(__fsub_rn(__fadd_rn(a.w, bb), mm), ssv), ee), 0.0f);
    return r;
}

// ---- DPP-based wave64 max reduction on u64 keys (result broadcast to all lanes) ----
template <int CTRL>
__device__ __forceinline__ unsigned long long wmax_step(unsigned long long k) {
    int lo = (int)(unsigned int)k;
    int hi = (int)(unsigned int)(k >> 32);
    int plo = __builtin_amdgcn_update_dpp(lo, lo, CTRL, 0xf, 0xf, false);
    int phi = __builtin_amdgcn_update_dpp(hi, hi, CTRL, 0xf, 0xf, false);
    unsigned long long p = ((unsigned long long)(unsigned int)phi << 32) | (unsigned int)plo;
    return (p > k) ? p : k;
}
__device__ __forceinline__ unsigned long long wave_max_u64(unsigned long long k) {
    k = wmax_step<0x111>(k);   // row_shr:1
    k = wmax_step<0x112>(k);   // row_shr:2
    k = wmax_step<0x114>(k);   // row_shr:4
    k = wmax_step<0x118>(k);   // row_shr:8  -> lane15 of each row has row max
    k = wmax_step<0x142>(k);   // row_bcast15
    k = wmax_step<0x143>(k);   // row_bcast31 -> lane63 has wave max
    unsigned int lo = (unsigned int)__builtin_amdgcn_readlane((int)(unsigned int)k, 63);
    unsigned int hi = (unsigned int)__builtin_amdgcn_readlane((int)(unsigned int)(k >> 32), 63);
    return ((unsigned long long)hi << 32) | lo;
}

// ---- FPS per-thread point storage: recursive struct of scalars (SROA-friendly).
template <int N> struct Pts {
    Pts<N - 1> rest;
    float px, py, pz, dist;
    unsigned int pid;
};
template <> struct Pts<0> {};

template <int N>
__device__ __forceinline__ void pts_load(Pts<N>& P, const float4* __restrict__ base,
                                         int t, int M,
                                         unsigned long long& bkey, float& bx, float& by, float& bz) {
    if constexpr (N > 0) {
        pts_load(P.rest, base, t, M, bkey, bx, by, bz);   // ascending J order
        constexpr int J = N - 1;
        int p = t + (J << 9);
        if (p < M) {
            float4 v = base[p];
            P.px = v.x; P.py = v.y; P.pz = v.z;
            P.pid = __float_as_uint(v.w);
            P.dist = 1e10f;
            unsigned long long k = (0xFFFFFFFFull << 32) | (unsigned int)(~P.pid);
            if (k > bkey) { bkey = k; bx = v.x; by = v.y; bz = v.z; }
        } else {
            P.px = P.py = P.pz = 0.0f; P.dist = 0.0f; P.pid = 0u;
        }
    }
}

template <int N>
__device__ __forceinline__ void pts_upd(Pts<N>& P, int t, int M,
                                        float cx, float cy, float cz,
                                        unsigned long long& bkey, float& bx, float& by, float& bz) {
    if constexpr (N > 0) {
        pts_upd(P.rest, t, M, cx, cy, cz, bkey, bx, by, bz);
        constexpr int J = N - 1;
        int p = t + (J << 9);
        if (p < M) {
            float dx = __fsub_rn(P.px, cx);
            float dy = __fsub_rn(P.py, cy);
            float dz = __fsub_rn(P.pz, cz);
            float d = __fadd_rn(__fadd_rn(__fmul_rn(dx, dx), __fmul_rn(dy, dy)), __fmul_rn(dz, dz));
            float nd = fminf(P.dist, d);
            P.dist = nd;
            // nd >= 0 always -> monotone key is just (bits | signbit)
            unsigned long long k = ((unsigned long long)(__float_as_uint(nd) | 0x80000000u) << 32)
                                   | (unsigned int)(~P.pid);
            if (k > bkey) { bkey = k; bx = P.px; by = P.py; bz = P.pz; }
        }
    }
}

// ---------------- K0: prep (transposes, bn scales, templates, cnt=0) ----------------
__global__ void k0_prep(const float* __restrict__ w_gh1, const float* __restrict__ w1,
                        const float* __restrict__ w2, const float* __restrict__ w3,
                        const float* __restrict__ gh_g, const float* __restrict__ gh_v,
                        const float* __restrict__ g1, const float* __restrict__ v1,
                        const float* __restrict__ g2, const float* __restrict__ v2,
                        float* __restrict__ ws) {
    int id = blockIdx.x * 256 + threadIdx.x;
    if (id < 65536) {
        int k = id & 255, o = id >> 8;
        ws[W_GH1T + k * 256 + o] = w_gh1[id];
    } else if (id < 131072) {
        int l = id - 65536; int k = l & 255, o = l >> 8;
        ws[W_W1T + k * 256 + o] = w1[l];
    } else if (id < 207872) {
        int l = id - 131072; int k = l & 255, o = l >> 8;
        ws[W_W2T + k * 320 + o] = w2[l];
    } else if (id < 297872) {
        int l = id - 207872; int k = l % 300, o = l / 300;
        ws[W_W3T + k * 320 + o] = w3[l];
    } else if (id < 298172) {
        int i = id - 297872;
        double phi = (sqrt(5.0) - 1.0) / 2.0;
        double zi = (2.0 * (double)i + 1.0) / 300.0 - 1.0;
        double r2 = 1.0 - zi * zi; if (r2 < 0.0) r2 = 0.0;
        double ri = sqrt(r2);
        double th = (6.283185307179586 * (double)i) * phi;
        ws[W_TMPL + i * 3 + 0] = (float)(ri * cos(th));
        ws[W_TMPL + i * 3 + 1] = (float)(ri * sin(th));
        ws[W_TMPL + i * 3 + 2] = (float)zi;
    } else if (id < 298428) {
        int i = id - 298172; ws[W_SGH + i] = gh_g[i] / sqrtf(gh_v[i] + 1e-5f);
    } else if (id < 298684) {
        int i = id - 298428; ws[W_SC1 + i] = g1[i] / sqrtf(v1[i] + 1e-5f);
    } else if (id < 298984) {
        int i = id - 298684; ws[W_SC2 + i] = g2[i] / sqrtf(v2[i] + 1e-5f);
    } else if (id < 298988) {
        ((int*)(ws + W_CNT))[id - 298984] = 0;
    }
}

// ---------------- K1: fused stage A (64-wide n-tile, named float4 accumulators) ----------------
// waves_per_eu(2,2): LDS (64KB) caps at 2 blocks/CU = 2 waves/EU anyway; clamping the
// MAX stops the RA from shedding pressure (spilling accumulators) to chase occupancy.
__global__ __launch_bounds__(256)
__attribute__((amdgpu_waves_per_eu(2, 2)))
void k1_stageA(
    const float* __restrict__ x,       // seed_features (B,256,20000)
    const float* __restrict__ wt,      // gh_w1^T [c][256]
    const float* __restrict__ b1g, const float* __restrict__ scg,
    const float* __restrict__ m1g, const float* __restrict__ be1g,
    const float* __restrict__ w2g, const float* __restrict__ b2g,   // (3,256),(3)
    float* __restrict__ out_grasp, float* __restrict__ out_obj, int* __restrict__ maskw) {
    __shared__ __align__(16) float Xs[256 * 64];   // 64 KB
    int b = blockIdx.y;
    int n0 = blockIdx.x * 64;
    int t = threadIdx.x;
    const float* xb = x + (size_t)b * CC * NN;
    #pragma unroll
    for (int k = 0; k < 16; k++) {
        int id = t + k * 256; int c = id >> 4; int u = id & 15;
        int n = n0 + u * 4;
        float4 v = make_float4(0.f, 0.f, 0.f, 0.f);
        if (n < NN) v = *(const float4*)(xb + (size_t)c * NN + n);
        *(float4*)(Xs + c * 64 + u * 4) = v;
    }
    __syncthreads();
    int og = (t >> 3) * 8;
    int n8 = (t & 7) * 8;
    float4 a0l = {0,0,0,0}, a0h = {0,0,0,0}, a1l = {0,0,0,0}, a1h = {0,0,0,0};
    float4 a2l = {0,0,0,0}, a2h = {0,0,0,0}, a3l = {0,0,0,0}, a3h = {0,0,0,0};
    float4 a4l = {0,0,0,0}, a4h = {0,0,0,0}, a5l = {0,0,0,0}, a5h = {0,0,0,0};
    float4 a6l = {0,0,0,0}, a6h = {0,0,0,0}, a7l = {0,0,0,0}, a7h = {0,0,0,0};
    #pragma unroll 2
    for (int c = 0; c < 256; c++) {
        float4 wva = *(const float4*)(wt + c * 256 + og);
        float4 wvb = *(const float4*)(wt + c * 256 + og + 4);
        float4 xva = *(const float4*)(Xs + c * 64 + n8);
        float4 xvb = *(const float4*)(Xs + c * 64 + n8 + 4);
        FMA4(a0l, wva.x, xva); FMA4(a0h, wva.x, xvb);
        FMA4(a1l, wva.y, xva); FMA4(a1h, wva.y, xvb);
        FMA4(a2l, wva.z, xva); FMA4(a2h, wva.z, xvb);
        FMA4(a3l, wva.w, xva); FMA4(a3h, wva.w, xvb);
        FMA4(a4l, wvb.x, xva); FMA4(a4h, wvb.x, xvb);
        FMA4(a5l, wvb.y, xva); FMA4(a5h, wvb.y, xvb);
        FMA4(a6l, wvb.z, xva); FMA4(a6h, wvb.z, xvb);
        FMA4(a7l, wvb.w, xva); FMA4(a7h, wvb.w, xvb);
    }
    __syncthreads();   // all reads of Xs done; reuse as h-tile
#define K1_EPI(I) { int o = og + I; \
    float bb = b1g[o], mm = m1g[o], ssv = scg[o], ee = be1g[o]; \
    *(float4*)(Xs + o * 64 + n8)     = bnrelu4(a##I##l, bb, mm, ssv, ee); \
    *(float4*)(Xs + o * 64 + n8 + 4) = bnrelu4(a##I##h, bb, mm, ssv, ee); }
    K1_EPI(0) K1_EPI(1) K1_EPI(2) K1_EPI(3)
    K1_EPI(4) K1_EPI(5) K1_EPI(6) K1_EPI(7)
#undef K1_EPI
    __syncthreads();
    if (t < 64) {
        float s0a = 0.0f, s1a = 0.0f, s2a = 0.0f;
        for (int c = 0; c < 256; c++) {
            float xv = Xs[c * 64 + t];
            s0a = fmaf(xv, w2g[c], s0a);
            s1a = fmaf(xv, w2g[256 + c], s1a);
            s2a = fmaf(xv, w2g[512 + c], s2a);
        }
        int n = n0 + t;
        if (n < NN) {
            float s0 = __fadd_rn(s0a, b2g[0]);
            float s1 = __fadd_rn(s1a, b2g[1]);
            float s2 = __fadd_rn(s2a, b2g[2]);
            bool obj = s1 > s0;
            bool gr = obj && (s2 > 0.1f);
            int gn = b * NN + n;
            out_grasp[gn] = s2;
            out_obj[gn] = obj ? 1.0f : 0.0f;
            maskw[gn] = gr ? 1 : 0;
        }
    }
}

// ---------------- K2: compact masked points ----------------
__global__ void k2_compact(const float* __restrict__ sx, const int* __restrict__ maskr,
                           int* __restrict__ cnt, float4* __restrict__ cpk) {
    int id = blockIdx.x * 256 + threadIdx.x;
    if (id >= BB * NN) return;
    int b = id / NN, n = id % NN;
    if (maskr[id]) {
        int pos = atomicAdd(cnt + b, 1);
        const float* p = sx + (size_t)id * 3;
        cpk[b * NN + pos] = make_float4(p[0], p[1], p[2], __uint_as_float((unsigned int)n));
    }
}

// ---------------- K3: FPS — 1 barrier/step, DPP wave reduce, dbuf winner slots ----------------
// waves_per_eu(2,2): clamp the backend's occupancy TARGET to 2 waves/EU (256-VGPR
// budget). r3/r4 evidence: with only the min set, the RA spilled the read-only
// px/py/pz/pid fields to scratch and re-read 16B x M x 1024 steps from HBM
// (FETCH 98.2/99.2 MB matches M=6000/6064 exactly); dist (RMW) stayed in VGPRs.
template <int PPT>
__global__ __launch_bounds__(512)
__attribute__((amdgpu_waves_per_eu(2, 2)))
void k3_fps(const float4* __restrict__ cpk,
            const int* __restrict__ cnt,
            float* __restrict__ out_inds,
            int* __restrict__ inds_i, int lo, int hi) {
    int b = blockIdx.x;
    int t = threadIdx.x;
    int M = cnt[b];
    int need = (M + 511) >> 9;
    if (!(need > lo && need <= hi)) return;   // exactly one variant proceeds per batch
    __shared__ unsigned long long skey[2][8];
    __shared__ __align__(16) float4 scd[2][8];
    if (M == 0) {
        for (int s = t; s < SS; s += 512) { out_inds[b * SS + s] = 0.0f; inds_i[b * SS + s] = 0; }
        return;
    }
    Pts<PPT> P;
    int wid = t >> 6, lane = t & 63;
    unsigned long long bkey = 0ull;
    float bx = 0, by = 0, bz = 0;
    pts_load(P, cpk + b * NN, t, M, bkey, bx, by, bz);
    // publish initial winner (start = first masked index)
    {
        unsigned long long wkey = wave_max_u64(bkey);
        unsigned long long mb = __ballot(bkey == wkey);
        if (lane == __ffsll((long long)mb) - 1) {
            skey[0][wid] = wkey;
            scd[0][wid] = make_float4(bx, by, bz, 0.0f);
        }
    }
    __syncthreads();
    int buf = 0;
    for (int step = 0; step < SS; step++) {
        // combine the 8 wave slots (broadcast LDS reads, done by every thread)
        unsigned long long wk = skey[buf][0];
        float4 c = scd[buf][0];
        #pragma unroll
        for (int i = 1; i < 8; i++) {
            unsigned long long k2 = skey[buf][i];
            float4 c2 = scd[buf][i];
            if (k2 > wk) { wk = k2; c = c2; }
        }
        unsigned int cid = ~(unsigned int)(wk & 0xFFFFFFFFull);
        if (t == 0) { out_inds[b * SS + step] = (float)cid; inds_i[b * SS + step] = (int)cid; }
        // distance update + per-lane best
        bkey = 0ull; bx = by = bz = 0.0f;
        pts_upd(P, t, M, c.x, c.y, c.z, bkey, bx, by, bz);
        unsigned long long wkey = wave_max_u64(bkey);
        unsigned long long mb = __ballot(bkey == wkey);
        if (lane == __ffsll((long long)mb) - 1) {
            skey[buf ^ 1][wid] = wkey;
            scd[buf ^ 1][wid] = make_float4(bx, by, bz, 0.0f);
        }
        __syncthreads();
        buf ^= 1;
    }
}

// ---------------- K4a: feature gather (one thread per output element) ----------------
__global__ void k4_gatherF(const float* __restrict__ sf, const int* __restrict__ inds,
                           float* __restrict__ o_feat) {
    int id = blockIdx.x * 256 + threadIdx.x;   // B*C*S = 1,048,576
    int s = id & (SS - 1);
    int bc = id >> 10;                          // b*C + c
    int b = bc >> 8;
    int idx = inds[(b << 10) | s];
    o_feat[id] = sf[(size_t)bc * NN + idx];
}

// ---------------- K4b: xyz + graspness gather ----------------
__global__ void k4_gatherX(const float* __restrict__ sx, const int* __restrict__ inds,
                           const float* __restrict__ grasp_all,
                           float* __restrict__ o_xyz, float* __restrict__ o_fg) {
    int id = blockIdx.x * 256 + threadIdx.x;   // 4096
    int b = id >> 10;
    int idx = inds[id];
    const float* p = sx + ((size_t)b * NN + idx) * 3;
    o_xyz[id * 3 + 0] = p[0];
    o_xyz[id * 3 + 1] = p[1];
    o_xyz[id * 3 + 2] = p[2];
    o_fg[id] = grasp_all[b * NN + idx];
}

// ---------------- K5: generic conv1x1 GEMM over 1024 pts (+optional bn+relu) ----------------
__global__ __launch_bounds__(256)
__attribute__((amdgpu_waves_per_eu(2, 2)))
void k5_gemm(const float* __restrict__ X, const float* __restrict__ WT,
             const float* __restrict__ bias, const float* __restrict__ scale,
             const float* __restrict__ mean, const float* __restrict__ beta,
             float* __restrict__ Y, int O, int Opad, int K, int relu_bn) {
    __shared__ __align__(16) float Xs[64 * 64];
    int b = blockIdx.z;
    int n0 = blockIdx.y * 64;
    int o0 = blockIdx.x * 64;
    int t = threadIdx.x;
    int o4 = o0 + (t & 15) * 4;
    int n4 = (t >> 4) * 4;
    float4 ac0 = {0,0,0,0}, ac1 = {0,0,0,0}, ac2 = {0,0,0,0}, ac3 = {0,0,0,0};
    const float* Xb = X + (size_t)b * K * SS;
    for (int c0 = 0; c0 < K; c0 += 64) {
        #pragma unroll
        for (int k = 0; k < 4; k++) {
            int id = t + k * 256; int cc = id >> 4; int nn4 = (id & 15) * 4;
            int c = c0 + cc;
            float4 v = make_float4(0.f, 0.f, 0.f, 0.f);
            if (c < K) v = *(const float4*)(Xb + (size_t)c * SS + n0 + nn4);
            *(float4*)(Xs + cc * 64 + nn4) = v;
        }
        __syncthreads();
        int kmax = (K - c0 < 64) ? (K - c0) : 64;
        for (int cc = 0; cc < kmax; cc++) {
            float4 wv = *(const float4*)(WT + (size_t)(c0 + cc) * Opad + o4);
            float4 xv = *(const float4*)(Xs + cc * 64 + n4);
            FMA4(ac0, wv.x, xv);
            FMA4(ac1, wv.y, xv);
            FMA4(ac2, wv.z, xv);
            FMA4(ac3, wv.w, xv);
        }
        __syncthreads();
    }
#define K5_EPI(I) { int o = o4 + I; if (o < O) { \
    float bb = bias[o]; float4 v; \
    if (relu_bn) { v = bnrelu4(ac##I, bb, mean[o], scale[o], beta[o]); } \
    else { v.x = __fadd_rn(ac##I.x, bb); v.y = __fadd_rn(ac##I.y, bb); \
           v.z = __fadd_rn(ac##I.z, bb); v.w = __fadd_rn(ac##I.w, bb); } \
    *(float4*)(Y + ((size_t)b * O + o) * SS + n0 + n4) = v; } }
    K5_EPI(0) K5_EPI(1) K5_EPI(2) K5_EPI(3)
#undef K5_EPI
}

// ---------------- K6: view max/argmax + rotations (reads s-major view_score) ----------------
// Runs AFTER k7; per-thread scan of a contiguous 300-float row (coalesced lines,
// full line utilization) replaces the old stride-4KB column walk over F3.
__global__ void k6_view(const float* __restrict__ Vs,   // view_score (B,1024,300)
                        const float* __restrict__ tmpl,
                        float* __restrict__ o_ti, float* __restrict__ o_ts,
                        float* __restrict__ o_vx, float* __restrict__ o_vr) {
    int id = blockIdx.x * 256 + threadIdx.x;   // 4096
    const float* f = Vs + (size_t)id * VV;
    float best = f[0];
    int bi = 0;
    for (int v = 1; v < VV; v++) {
        float x = f[v];
        if (x > best) { best = x; bi = v; }   // strict > keeps first max
    }
    o_ti[id] = (float)bi;
    o_ts[id] = best;
    float tx = tmpl[bi * 3 + 0], ty = tmpl[bi * 3 + 1], tz = tmpl[bi * 3 + 2];
    o_vx[id * 3 + 0] = tx; o_vx[id * 3 + 1] = ty; o_vx[id * 3 + 2] = tz;
    // towards = -vp_xyz
    float ax0 = -tx, ax1 = -ty, ax2 = -tz;
    float ay0 = ty, ay1 = -tx, ay2 = 0.0f;   // (-ax1, ax0, 0)
    float ny = sqrtf(__fadd_rn(__fadd_rn(__fmul_rn(ay0, ay0), __fmul_rn(ay1, ay1)), __fmul_rn(ay2, ay2)));
    if (ny == 0.0f) { ay0 = 0.0f; ay1 = 1.0f; ay2 = 0.0f; }
    float nx = sqrtf(__fadd_rn(__fadd_rn(__fmul_rn(ax0, ax0), __fmul_rn(ax1, ax1)), __fmul_rn(ax2, ax2)));
    ax0 = ax0 / nx; ax1 = ax1 / nx; ax2 = ax2 / nx;
    float ny2 = sqrtf(__fadd_rn(__fadd_rn(__fmul_rn(ay0, ay0), __fmul_rn(ay1, ay1)), __fmul_rn(ay2, ay2)));
    ay0 = ay0 / ny2; ay1 = ay1 / ny2; ay2 = ay2 / ny2;
    float az0 = __fsub_rn(__fmul_rn(ax1, ay2), __fmul_rn(ax2, ay1));
    float az1 = __fsub_rn(__fmul_rn(ax2, ay0), __fmul_rn(ax0, ay2));
    float az2 = __fsub_rn(__fmul_rn(ax0, ay1), __fmul_rn(ax1, ay0));
    float* R = o_vr + (size_t)id * 9;   // columns = (ax, ay, az)
    R[0] = ax0; R[1] = ay0; R[2] = az0;
    R[3] = ax1; R[4] = ay1; R[5] = az1;
    R[6] = ax2; R[7] = ay2; R[8] = az2;
}

// ---------------- K7: transpose f3 (B,300,1024) -> view_score (B,1024,300) ----------------
__global__ void k7_transpose(const float* __restrict__ F3v, float* __restrict__ outp) {
    __shared__ float T[64][65];
    int b = blockIdx.z;
    int s0 = blockIdx.y * 64;
    int v0 = blockIdx.x * 64;
    int t = threadIdx.x;
    int sc = t & 63;
    int g = t >> 6;
    #pragma unroll
    for (int k = 0; k < 16; k++) {
        int vr = g * 16 + k;
        int v = v0 + vr;
        T[vr][sc] = (v < VV) ? F3v[((size_t)b * VV + v) * SS + s0 + sc] : 0.0f;
    }
    __syncthreads();
    #pragma unroll
    for (int k = 0; k < 16; k++) {
        int sr = g * 16 + k;
        int v = v0 + sc;
        if (v < VV)
            outp[((size_t)b * SS + (s0 + sr)) * VV + v] = T[sc][sr];
    }
}

extern "C" void kernel_launch(void* const* d_in, const int* in_sizes, int n_in,
                              void* d_out, int out_size, void* d_ws, size_t ws_size,
                              hipStream_t stream) {
    const float* seed_xyz  = (const float*)d_in[0];
    const float* seed_feat = (const float*)d_in[1];
    const float* gh_w1 = (const float*)d_in[2];
    const float* gh_b1 = (const float*)d_in[3];
    const float* gh_g1 = (const float*)d_in[4];
    const float* gh_be1 = (const float*)d_in[5];
    const float* gh_m1 = (const float*)d_in[6];
    const float* gh_v1 = (const float*)d_in[7];
    const float* gh_w2 = (const float*)d_in[8];
    const float* gh_b2 = (const float*)d_in[9];
    const float* w1 = (const float*)d_in[10];
    const float* b1 = (const float*)d_in[11];
    const float* g1 = (const float*)d_in[12];
    const float* be1 = (const float*)d_in[13];
    const float* m1 = (const float*)d_in[14];
    const float* v1 = (const float*)d_in[15];
    const float* w2 = (const float*)d_in[16];
    const float* b2 = (const float*)d_in[17];
    const float* g2 = (const float*)d_in[18];
    const float* be2 = (const float*)d_in[19];
    const float* m2 = (const float*)d_in[20];
    const float* v2 = (const float*)d_in[21];
    const float* w3 = (const float*)d_in[22];
    const float* b3 = (const float*)d_in[23];

    float* out = (float*)d_out;
    float* ws = (float*)d_ws;
    int* cnt = (int*)(ws + W_CNT);
    float4* cpk = (float4*)(ws + W_CPK);
    int* inds_i = (int*)(ws + W_INDS);
    int* maskw = (int*)(ws + W_MASK);

    // K0: prep
    k0_prep<<<dim3((298988 + 255) / 256), dim3(256), 0, stream>>>(
        gh_w1, w1, w2, w3, gh_g1, gh_v1, g1, v1, g2, v2, ws);

    // K1: fused stage A (64-wide tiles)
    k1_stageA<<<dim3((NN + 63) / 64, BB), dim3(256), 0, stream>>>(
        seed_feat, ws + W_GH1T, gh_b1, ws + W_SGH, gh_m1, gh_be1, gh_w2, gh_b2,
        out + O_GRASP, out + O_OBJ, maskw);

    // K2: compaction
    k2_compact<<<dim3((BB * NN + 255) / 256), dim3(256), 0, stream>>>(seed_xyz, maskw, cnt, cpk);

    // K3: FPS (three self-selecting register-capacity variants)
    k3_fps<13><<<dim3(BB), dim3(512), 0, stream>>>(cpk, cnt, out + O_INDS, inds_i, -1, 13);
    k3_fps<26><<<dim3(BB), dim3(512), 0, stream>>>(cpk, cnt, out + O_INDS, inds_i, 13, 26);
    k3_fps<40><<<dim3(BB), dim3(512), 0, stream>>>(cpk, cnt, out + O_INDS, inds_i, 26, 40);

    // K4: gathers
    k4_gatherF<<<dim3(BB * CC * SS / 256), dim3(256), 0, stream>>>(seed_feat, inds_i, out + O_GFEAT);
    k4_gatherX<<<dim3(BB * SS / 256), dim3(256), 0, stream>>>(
        seed_xyz, inds_i, out + O_GRASP, out + O_GXYZ, out + O_FPG);

    // K5: stage C MLP (three conv1x1 layers)
    k5_gemm<<<dim3(4, 16, BB), dim3(256), 0, stream>>>(
        out + O_GFEAT, ws + W_W1T, b1, ws + W_SC1, m1, be1, ws + W_F1, 256, 256, 256, 1);
    k5_gemm<<<dim3(5, 16, BB), dim3(256), 0, stream>>>(
        ws + W_F1, ws + W_W2T, b2, ws + W_SC2, m2, be2, ws + W_F2, 300, 320, 256, 1);
    k5_gemm<<<dim3(5, 16, BB), dim3(256), 0, stream>>>(
        ws + W_F2, ws + W_W3T, b3, b3, b3, b3, ws + W_F3, 300, 320, 300, 0);

    // K7: view_score transpose (before K6, which reads it)
    k7_transpose<<<dim3(5, 16, BB), dim3(256), 0, stream>>>(ws + W_F3, out + O_VIEW);

    // K6: view argmax + rotations (reads transposed view_score)
    k6_view<<<dim3(BB * SS / 256), dim3(256), 0, stream>>>(
        out + O_VIEW, ws + W_TMPL, out + O_TVI, out + O_TVS, out + O_VPX, out + O_VPR);
}

// Round 6
// 1449.277 us; speedup vs baseline: 1.2934x; 1.0265x over previous
//
#include <hip/hip_runtime.h>
#include <math.h>

// ---------------- problem constants ----------------
#define BB 4
#define NN 20000
#define CC 256
#define VV 300
#define SS 1024

// output float offsets (concatenated flat, all read back as float32)
#define O_GRASP   0          // (4,20000)
#define O_OBJ     80000      // (4,20000)
#define O_GXYZ    160000     // (4,1024,3)
#define O_INDS    172288     // (4,1024)
#define O_GFEAT   176384     // (4,256,1024)
#define O_FPG     1224960    // (4,1024)
#define O_VIEW    1229056    // (4,1024,300)
#define O_TVI     2457856    // (4,1024)
#define O_TVS     2461952    // (4,1024)
#define O_VPX     2466048    // (4,1024,3)
#define O_VPR     2478336    // (4,1024,3,3)

// ws float offsets
#define W_GH1T    0          // [256 c][256 o]
#define W_W1T     65536      // [256 c][256 o]
#define W_W2T     131072     // [256 c][320 o-pad] (O=300)
#define W_W3T     212992     // [300 c][320 o-pad] (O=300)
#define W_TMPL    308992     // 300*3
#define W_SGH     309892     // 256
#define W_SC1     310148     // 256
#define W_SC2     310404     // 300
#define W_CNT     310704     // 4 ints (pad to 310720)
#define W_CPK     310720     // 4*20000 float4 (x,y,z,idx-bits)
#define W_INDS    630720     // 4*1024 int
#define W_MASK    634816     // 4*20000 int
#define W_F1      714816     // 4*256*1024
#define W_F2      1763392    // 4*300*1024
#define W_F3      2992192    // 4*300*1024  (end 4220992 floats = 16.9 MB)

// FMA a 4-vector accumulator: A += W * X (componentwise), exact fmaf per element.
#define FMA4(A, W, X) do { \
    A.x = fmaf((W), (X).x, A.x); \
    A.y = fmaf((W), (X).y, A.y); \
    A.z = fmaf((W), (X).z, A.z); \
    A.w = fmaf((W), (X).w, A.w); } while (0)

__device__ __forceinline__ float4 bnrelu4(float4 a, float bb, float mm, float ssv, float ee) {
    float4 r;
    r.x = fmaxf(__fadd_rn(__fmul_rn(__fsub_rn(__fadd_rn(a.x, bb), mm), ssv), ee), 0.0f);
    r.y = fmaxf(__fadd_rn(__fmul_rn(__fsub_rn(__fadd_rn(a.y, bb), mm), ssv), ee), 0.0f);
    r.z = fmaxf(__fadd_rn(__fmul_rn(__fsub_rn(__fadd_rn(a.z, bb), mm), ssv), ee), 0.0f);
    r.w = fmaxf(__fadd_rn(__fmul_rn(__fsub_rn(__fadd_rn(a.w, bb), mm), ssv), ee), 0.0f);
    return r;
}

// ---- DPP-based wave64 max reduction on u64 keys (result broadcast to all lanes) ----
template <int CTRL>
__device__ __forceinline__ unsigned long long wmax_step(unsigned long long k) {
    int lo = (int)(unsigned int)k;
    int hi = (int)(unsigned int)(k >> 32);
    int plo = __builtin_amdgcn_update_dpp(lo, lo, CTRL, 0xf, 0xf, false);
    int phi = __builtin_amdgcn_update_dpp(hi, hi, CTRL, 0xf, 0xf, false);
    unsigned long long p = ((unsigned long long)(unsigned int)phi << 32) | (unsigned int)plo;
    return (p > k) ? p : k;
}
__device__ __forceinline__ unsigned long long wave_max_u64(unsigned long long k) {
    k = wmax_step<0x111>(k);   // row_shr:1
    k = wmax_step<0x112>(k);   // row_shr:2
    k = wmax_step<0x114>(k);   // row_shr:4
    k = wmax_step<0x118>(k);   // row_shr:8  -> lane15 of each row has row max
    k = wmax_step<0x142>(k);   // row_bcast15
    k = wmax_step<0x143>(k);   // row_bcast31 -> lane63 has wave max
    unsigned int lo = (unsigned int)__builtin_amdgcn_readlane((int)(unsigned int)k, 63);
    unsigned int hi = (unsigned int)__builtin_amdgcn_readlane((int)(unsigned int)(k >> 32), 63);
    return ((unsigned long long)hi << 32) | lo;
}

// ---- FPS per-thread point storage: recursive struct of scalars (SROA-friendly).
// klo = ~pid precomputed: key lo-word select becomes a constant pick.
template <int N> struct Pts {
    Pts<N - 1> rest;
    float px, py, pz, dist;
    unsigned int klo;
};
template <> struct Pts<0> {};

template <int N>
__device__ __forceinline__ void pts_load(Pts<N>& P, const float4* __restrict__ base,
                                         int t, int M,
                                         unsigned long long& bkey, float& bx, float& by, float& bz) {
    if constexpr (N > 0) {
        pts_load(P.rest, base, t, M, bkey, bx, by, bz);   // ascending J order
        constexpr int J = N - 1;
        int p = t + (J << 8);          // 256-thread stride
        if (p < M) {
            float4 v = base[p];
            P.px = v.x; P.py = v.y; P.pz = v.z;
            P.klo = ~__float_as_uint(v.w);
            P.dist = 1e10f;
            unsigned long long k = (0xFFFFFFFFull << 32) | P.klo;
            if (k > bkey) { bkey = k; bx = v.x; by = v.y; bz = v.z; }
        } else {
            P.px = P.py = P.pz = 0.0f; P.dist = 0.0f; P.klo = 0u;
        }
    }
}

template <int N>
__device__ __forceinline__ void pts_upd(Pts<N>& P, int t, int M,
                                        float cx, float cy, float cz,
                                        unsigned long long& bkey, float& bx, float& by, float& bz) {
    if constexpr (N > 0) {
        pts_upd(P.rest, t, M, cx, cy, cz, bkey, bx, by, bz);
        constexpr int J = N - 1;
        int p = t + (J << 8);
        if (p < M) {
            float dx = __fsub_rn(P.px, cx);
            float dy = __fsub_rn(P.py, cy);
            float dz = __fsub_rn(P.pz, cz);
            float d = __fadd_rn(__fadd_rn(__fmul_rn(dx, dx), __fmul_rn(dy, dy)), __fmul_rn(dz, dz));
            float nd = fminf(P.dist, d);
            P.dist = nd;
            // nd >= 0 always -> raw f32 bits are monotone (no sign-or needed)
            unsigned long long k = ((unsigned long long)__float_as_uint(nd) << 32) | P.klo;
            if (k > bkey) { bkey = k; bx = P.px; by = P.py; bz = P.pz; }
        }
    }
}

// ---------------- K0: prep (transposes, bn scales, templates, cnt=0) ----------------
__global__ void k0_prep(const float* __restrict__ w_gh1, const float* __restrict__ w1,
                        const float* __restrict__ w2, const float* __restrict__ w3,
                        const float* __restrict__ gh_g, const float* __restrict__ gh_v,
                        const float* __restrict__ g1, const float* __restrict__ v1,
                        const float* __restrict__ g2, const float* __restrict__ v2,
                        float* __restrict__ ws) {
    int id = blockIdx.x * 256 + threadIdx.x;
    if (id < 65536) {
        int k = id & 255, o = id >> 8;
        ws[W_GH1T + k * 256 + o] = w_gh1[id];
    } else if (id < 131072) {
        int l = id - 65536; int k = l & 255, o = l >> 8;
        ws[W_W1T + k * 256 + o] = w1[l];
    } else if (id < 207872) {
        int l = id - 131072; int k = l & 255, o = l >> 8;
        ws[W_W2T + k * 320 + o] = w2[l];
    } else if (id < 297872) {
        int l = id - 207872; int k = l % 300, o = l / 300;
        ws[W_W3T + k * 320 + o] = w3[l];
    } else if (id < 298172) {
        int i = id - 297872;
        double phi = (sqrt(5.0) - 1.0) / 2.0;
        double zi = (2.0 * (double)i + 1.0) / 300.0 - 1.0;
        double r2 = 1.0 - zi * zi; if (r2 < 0.0) r2 = 0.0;
        double ri = sqrt(r2);
        double th = (6.283185307179586 * (double)i) * phi;
        ws[W_TMPL + i * 3 + 0] = (float)(ri * cos(th));
        ws[W_TMPL + i * 3 + 1] = (float)(ri * sin(th));
        ws[W_TMPL + i * 3 + 2] = (float)zi;
    } else if (id < 298428) {
        int i = id - 298172; ws[W_SGH + i] = gh_g[i] / sqrtf(gh_v[i] + 1e-5f);
    } else if (id < 298684) {
        int i = id - 298428; ws[W_SC1 + i] = g1[i] / sqrtf(v1[i] + 1e-5f);
    } else if (id < 298984) {
        int i = id - 298684; ws[W_SC2 + i] = g2[i] / sqrtf(v2[i] + 1e-5f);
    } else if (id < 298988) {
        ((int*)(ws + W_CNT))[id - 298984] = 0;
    }
}

// ---------------- K1: fused stage A (64-wide n-tile, named float4 accumulators) ----------------
__global__ __launch_bounds__(256)
__attribute__((amdgpu_waves_per_eu(2, 2)))
void k1_stageA(
    const float* __restrict__ x,       // seed_features (B,256,20000)
    const float* __restrict__ wt,      // gh_w1^T [c][256]
    const float* __restrict__ b1g, const float* __restrict__ scg,
    const float* __restrict__ m1g, const float* __restrict__ be1g,
    const float* __restrict__ w2g, const float* __restrict__ b2g,   // (3,256),(3)
    float* __restrict__ out_grasp, float* __restrict__ out_obj, int* __restrict__ maskw) {
    __shared__ __align__(16) float Xs[256 * 64];   // 64 KB
    int b = blockIdx.y;
    int n0 = blockIdx.x * 64;
    int t = threadIdx.x;
    const float* xb = x + (size_t)b * CC * NN;
    #pragma unroll
    for (int k = 0; k < 16; k++) {
        int id = t + k * 256; int c = id >> 4; int u = id & 15;
        int n = n0 + u * 4;
        float4 v = make_float4(0.f, 0.f, 0.f, 0.f);
        if (n < NN) v = *(const float4*)(xb + (size_t)c * NN + n);
        *(float4*)(Xs + c * 64 + u * 4) = v;
    }
    __syncthreads();
    int og = (t >> 3) * 8;
    int n8 = (t & 7) * 8;
    float4 a0l = {0,0,0,0}, a0h = {0,0,0,0}, a1l = {0,0,0,0}, a1h = {0,0,0,0};
    float4 a2l = {0,0,0,0}, a2h = {0,0,0,0}, a3l = {0,0,0,0}, a3h = {0,0,0,0};
    float4 a4l = {0,0,0,0}, a4h = {0,0,0,0}, a5l = {0,0,0,0}, a5h = {0,0,0,0};
    float4 a6l = {0,0,0,0}, a6h = {0,0,0,0}, a7l = {0,0,0,0}, a7h = {0,0,0,0};
    #pragma unroll 2
    for (int c = 0; c < 256; c++) {
        float4 wva = *(const float4*)(wt + c * 256 + og);
        float4 wvb = *(const float4*)(wt + c * 256 + og + 4);
        float4 xva = *(const float4*)(Xs + c * 64 + n8);
        float4 xvb = *(const float4*)(Xs + c * 64 + n8 + 4);
        FMA4(a0l, wva.x, xva); FMA4(a0h, wva.x, xvb);
        FMA4(a1l, wva.y, xva); FMA4(a1h, wva.y, xvb);
        FMA4(a2l, wva.z, xva); FMA4(a2h, wva.z, xvb);
        FMA4(a3l, wva.w, xva); FMA4(a3h, wva.w, xvb);
        FMA4(a4l, wvb.x, xva); FMA4(a4h, wvb.x, xvb);
        FMA4(a5l, wvb.y, xva); FMA4(a5h, wvb.y, xvb);
        FMA4(a6l, wvb.z, xva); FMA4(a6h, wvb.z, xvb);
        FMA4(a7l, wvb.w, xva); FMA4(a7h, wvb.w, xvb);
    }
    __syncthreads();   // all reads of Xs done; reuse as h-tile
#define K1_EPI(I) { int o = og + I; \
    float bb = b1g[o], mm = m1g[o], ssv = scg[o], ee = be1g[o]; \
    *(float4*)(Xs + o * 64 + n8)     = bnrelu4(a##I##l, bb, mm, ssv, ee); \
    *(float4*)(Xs + o * 64 + n8 + 4) = bnrelu4(a##I##h, bb, mm, ssv, ee); }
    K1_EPI(0) K1_EPI(1) K1_EPI(2) K1_EPI(3)
    K1_EPI(4) K1_EPI(5) K1_EPI(6) K1_EPI(7)
#undef K1_EPI
    __syncthreads();
    if (t < 64) {
        float s0a = 0.0f, s1a = 0.0f, s2a = 0.0f;
        for (int c = 0; c < 256; c++) {
            float xv = Xs[c * 64 + t];
            s0a = fmaf(xv, w2g[c], s0a);
            s1a = fmaf(xv, w2g[256 + c], s1a);
            s2a = fmaf(xv, w2g[512 + c], s2a);
        }
        int n = n0 + t;
        if (n < NN) {
            float s0 = __fadd_rn(s0a, b2g[0]);
            float s1 = __fadd_rn(s1a, b2g[1]);
            float s2 = __fadd_rn(s2a, b2g[2]);
            bool obj = s1 > s0;
            bool gr = obj && (s2 > 0.1f);
            int gn = b * NN + n;
            out_grasp[gn] = s2;
            out_obj[gn] = obj ? 1.0f : 0.0f;
            maskw[gn] = gr ? 1 : 0;
        }
    }
}

// ---------------- K2: compact masked points (wave-aggregated atomics) ----------------
// r5 theory: 20000 same-address serialized atomics/batch ~ tens of µs. One atomic
// per wave instead (ballot + prefix-popcount). Compaction order changes: harmless,
// FPS selection depends only on the point set + pid tiebreak.
__global__ void k2_compact(const float* __restrict__ sx, const int* __restrict__ maskr,
                           int* __restrict__ cnt, float4* __restrict__ cpk) {
    int n = blockIdx.x * 256 + threadIdx.x;
    int b = blockIdx.y;
    bool take = (n < NN) && (maskr[b * NN + n] != 0);
    unsigned long long m = __ballot(take);
    if (take) {
        int lane = threadIdx.x & 63;
        int lead = __ffsll((long long)m) - 1;
        int base = 0;
        if (lane == lead) base = atomicAdd(cnt + b, __popcll(m));
        base = __shfl(base, lead);
        int pos = base + __popcll(m & ((1ull << lane) - 1ull));
        const float* p = sx + ((size_t)b * NN + n) * 3;
        cpk[b * NN + pos] = make_float4(p[0], p[1], p[2], __uint_as_float((unsigned int)n));
    }
}

// ---------------- K3: FPS — 256 thr / 4 waves, 1 barrier/step, DPP reduce ----------------
// r5 post-mortem: FETCH_SIZE is KB (~96KB = legit cpk read) — never memory-bound.
// Issue+latency bound: 4-slot combine (was 8), 4-wave barrier (was 8), sign-or
// dropped (dist>=0 -> raw bits monotone), ~pid precomputed at load.
template <int PPT>
__global__ __launch_bounds__(256)
__attribute__((amdgpu_waves_per_eu(1, 1)))
void k3_fps(const float4* __restrict__ cpk,
            const int* __restrict__ cnt,
            float* __restrict__ out_inds,
            int* __restrict__ inds_i, int lo, int hi) {
    int b = blockIdx.x;
    int t = threadIdx.x;
    int M = cnt[b];
    int need = (M + 255) >> 8;
    if (!(need > lo && need <= hi)) return;   // exactly one variant proceeds per batch
    __shared__ unsigned long long skey[2][4];
    __shared__ __align__(16) float4 scd[2][4];
    if (M == 0) {
        for (int s = t; s < SS; s += 256) { out_inds[b * SS + s] = 0.0f; inds_i[b * SS + s] = 0; }
        return;
    }
    Pts<PPT> P;
    int wid = t >> 6, lane = t & 63;
    unsigned long long bkey = 0ull;
    float bx = 0, by = 0, bz = 0;
    pts_load(P, cpk + b * NN, t, M, bkey, bx, by, bz);
    // publish initial winner (start = first masked index)
    {
        unsigned long long wkey = wave_max_u64(bkey);
        unsigned long long mb = __ballot(bkey == wkey);
        if (lane == __ffsll((long long)mb) - 1) {
            skey[0][wid] = wkey;
            scd[0][wid] = make_float4(bx, by, bz, 0.0f);
        }
    }
    __syncthreads();
    int buf = 0;
    for (int step = 0; step < SS; step++) {
        // combine the 4 wave slots (broadcast LDS reads, done by every thread)
        unsigned long long wk = skey[buf][0];
        float4 c = scd[buf][0];
        #pragma unroll
        for (int i = 1; i < 4; i++) {
            unsigned long long k2 = skey[buf][i];
            float4 c2 = scd[buf][i];
            if (k2 > wk) { wk = k2; c = c2; }
        }
        unsigned int cid = ~(unsigned int)(wk & 0xFFFFFFFFull);
        if (t == 0) { out_inds[b * SS + step] = (float)cid; inds_i[b * SS + step] = (int)cid; }
        // distance update + per-lane best
        bkey = 0ull; bx = by = bz = 0.0f;
        pts_upd(P, t, M, c.x, c.y, c.z, bkey, bx, by, bz);
        unsigned long long wkey = wave_max_u64(bkey);
        unsigned long long mb = __ballot(bkey == wkey);
        if (lane == __ffsll((long long)mb) - 1) {
            skey[buf ^ 1][wid] = wkey;
            scd[buf ^ 1][wid] = make_float4(bx, by, bz, 0.0f);
        }
        __syncthreads();
        buf ^= 1;
    }
}

// ---------------- K4a: feature gather (one thread per output element) ----------------
__global__ void k4_gatherF(const float* __restrict__ sf, const int* __restrict__ inds,
                           float* __restrict__ o_feat) {
    int id = blockIdx.x * 256 + threadIdx.x;   // B*C*S = 1,048,576
    int s = id & (SS - 1);
    int bc = id >> 10;                          // b*C + c
    int b = bc >> 8;
    int idx = inds[(b << 10) | s];
    o_feat[id] = sf[(size_t)bc * NN + idx];
}

// ---------------- K4b: xyz + graspness gather ----------------
__global__ void k4_gatherX(const float* __restrict__ sx, const int* __restrict__ inds,
                           const float* __restrict__ grasp_all,
                           float* __restrict__ o_xyz, float* __restrict__ o_fg) {
    int id = blockIdx.x * 256 + threadIdx.x;   // 4096
    int b = id >> 10;
    int idx = inds[id];
    const float* p = sx + ((size_t)b * NN + idx) * 3;
    o_xyz[id * 3 + 0] = p[0];
    o_xyz[id * 3 + 1] = p[1];
    o_xyz[id * 3 + 2] = p[2];
    o_fg[id] = grasp_all[b * NN + idx];
}

// ---------------- K5: generic conv1x1 GEMM over 1024 pts (+optional bn+relu) ----------------
__global__ __launch_bounds__(256)
__attribute__((amdgpu_waves_per_eu(2, 2)))
void k5_gemm(const float* __restrict__ X, const float* __restrict__ WT,
             const float* __restrict__ bias, const float* __restrict__ scale,
             const float* __restrict__ mean, const float* __restrict__ beta,
             float* __restrict__ Y, int O, int Opad, int K, int relu_bn) {
    __shared__ __align__(16) float Xs[64 * 64];
    int b = blockIdx.z;
    int n0 = blockIdx.y * 64;
    int o0 = blockIdx.x * 64;
    int t = threadIdx.x;
    int o4 = o0 + (t & 15) * 4;
    int n4 = (t >> 4) * 4;
    float4 ac0 = {0,0,0,0}, ac1 = {0,0,0,0}, ac2 = {0,0,0,0}, ac3 = {0,0,0,0};
    const float* Xb = X + (size_t)b * K * SS;
    for (int c0 = 0; c0 < K; c0 += 64) {
        #pragma unroll
        for (int k = 0; k < 4; k++) {
            int id = t + k * 256; int cc = id >> 4; int nn4 = (id & 15) * 4;
            int c = c0 + cc;
            float4 v = make_float4(0.f, 0.f, 0.f, 0.f);
            if (c < K) v = *(const float4*)(Xb + (size_t)c * SS + n0 + nn4);
            *(float4*)(Xs + cc * 64 + nn4) = v;
        }
        __syncthreads();
        int kmax = (K - c0 < 64) ? (K - c0) : 64;
        for (int cc = 0; cc < kmax; cc++) {
            float4 wv = *(const float4*)(WT + (size_t)(c0 + cc) * Opad + o4);
            float4 xv = *(const float4*)(Xs + cc * 64 + n4);
            FMA4(ac0, wv.x, xv);
            FMA4(ac1, wv.y, xv);
            FMA4(ac2, wv.z, xv);
            FMA4(ac3, wv.w, xv);
        }
        __syncthreads();
    }
#define K5_EPI(I) { int o = o4 + I; if (o < O) { \
    float bb = bias[o]; float4 v; \
    if (relu_bn) { v = bnrelu4(ac##I, bb, mean[o], scale[o], beta[o]); } \
    else { v.x = __fadd_rn(ac##I.x, bb); v.y = __fadd_rn(ac##I.y, bb); \
           v.z = __fadd_rn(ac##I.z, bb); v.w = __fadd_rn(ac##I.w, bb); } \
    *(float4*)(Y + ((size_t)b * O + o) * SS + n0 + n4) = v; } }
    K5_EPI(0) K5_EPI(1) K5_EPI(2) K5_EPI(3)
#undef K5_EPI
}

// ---------------- K6: view max/argmax + rotations (reads s-major view_score) ----------------
__global__ void k6_view(const float* __restrict__ Vs,   // view_score (B,1024,300)
                        const float* __restrict__ tmpl,
                        float* __restrict__ o_ti, float* __restrict__ o_ts,
                        float* __restrict__ o_vx, float* __restrict__ o_vr) {
    int id = blockIdx.x * 256 + threadIdx.x;   // 4096
    const float* f = Vs + (size_t)id * VV;
    float best = f[0];
    int bi = 0;
    for (int v = 1; v < VV; v++) {
        float x = f[v];
        if (x > best) { best = x; bi = v; }   // strict > keeps first max
    }
    o_ti[id] = (float)bi;
    o_ts[id] = best;
    float tx = tmpl[bi * 3 + 0], ty = tmpl[bi * 3 + 1], tz = tmpl[bi * 3 + 2];
    o_vx[id * 3 + 0] = tx; o_vx[id * 3 + 1] = ty; o_vx[id * 3 + 2] = tz;
    // towards = -vp_xyz
    float ax0 = -tx, ax1 = -ty, ax2 = -tz;
    float ay0 = ty, ay1 = -tx, ay2 = 0.0f;   // (-ax1, ax0, 0)
    float ny = sqrtf(__fadd_rn(__fadd_rn(__fmul_rn(ay0, ay0), __fmul_rn(ay1, ay1)), __fmul_rn(ay2, ay2)));
    if (ny == 0.0f) { ay0 = 0.0f; ay1 = 1.0f; ay2 = 0.0f; }
    float nx = sqrtf(__fadd_rn(__fadd_rn(__fmul_rn(ax0, ax0), __fmul_rn(ax1, ax1)), __fmul_rn(ax2, ax2)));
    ax0 = ax0 / nx; ax1 = ax1 / nx; ax2 = ax2 / nx;
    float ny2 = sqrtf(__fadd_rn(__fadd_rn(__fmul_rn(ay0, ay0), __fmul_rn(ay1, ay1)), __fmul_rn(ay2, ay2)));
    ay0 = ay0 / ny2; ay1 = ay1 / ny2; ay2 = ay2 / ny2;
    float az0 = __fsub_rn(__fmul_rn(ax1, ay2), __fmul_rn(ax2, ay1));
    float az1 = __fsub_rn(__fmul_rn(ax2, ay0), __fmul_rn(ax0, ay2));
    float az2 = __fsub_rn(__fmul_rn(ax0, ay1), __fmul_rn(ax1, ay0));
    float* R = o_vr + (size_t)id * 9;   // columns = (ax, ay, az)
    R[0] = ax0; R[1] = ay0; R[2] = az0;
    R[3] = ax1; R[4] = ay1; R[5] = az1;
    R[6] = ax2; R[7] = ay2; R[8] = az2;
}

// ---------------- K7: transpose f3 (B,300,1024) -> view_score (B,1024,300) ----------------
__global__ void k7_transpose(const float* __restrict__ F3v, float* __restrict__ outp) {
    __shared__ float T[64][65];
    int b = blockIdx.z;
    int s0 = blockIdx.y * 64;
    int v0 = blockIdx.x * 64;
    int t = threadIdx.x;
    int sc = t & 63;
    int g = t >> 6;
    #pragma unroll
    for (int k = 0; k < 16; k++) {
        int vr = g * 16 + k;
        int v = v0 + vr;
        T[vr][sc] = (v < VV) ? F3v[((size_t)b * VV + v) * SS + s0 + sc] : 0.0f;
    }
    __syncthreads();
    #pragma unroll
    for (int k = 0; k < 16; k++) {
        int sr = g * 16 + k;
        int v = v0 + sc;
        if (v < VV)
            outp[((size_t)b * SS + (s0 + sr)) * VV + v] = T[sc][sr];
    }
}

extern "C" void kernel_launch(void* const* d_in, const int* in_sizes, int n_in,
                              void* d_out, int out_size, void* d_ws, size_t ws_size,
                              hipStream_t stream) {
    const float* seed_xyz  = (const float*)d_in[0];
    const float* seed_feat = (const float*)d_in[1];
    const float* gh_w1 = (const float*)d_in[2];
    const float* gh_b1 = (const float*)d_in[3];
    const float* gh_g1 = (const float*)d_in[4];
    const float* gh_be1 = (const float*)d_in[5];
    const float* gh_m1 = (const float*)d_in[6];
    const float* gh_v1 = (const float*)d_in[7];
    const float* gh_w2 = (const float*)d_in[8];
    const float* gh_b2 = (const float*)d_in[9];
    const float* w1 = (const float*)d_in[10];
    const float* b1 = (const float*)d_in[11];
    const float* g1 = (const float*)d_in[12];
    const float* be1 = (const float*)d_in[13];
    const float* m1 = (const float*)d_in[14];
    const float* v1 = (const float*)d_in[15];
    const float* w2 = (const float*)d_in[16];
    const float* b2 = (const float*)d_in[17];
    const float* g2 = (const float*)d_in[18];
    const float* be2 = (const float*)d_in[19];
    const float* m2 = (const float*)d_in[20];
    const float* v2 = (const float*)d_in[21];
    const float* w3 = (const float*)d_in[22];
    const float* b3 = (const float*)d_in[23];

    float* out = (float*)d_out;
    float* ws = (float*)d_ws;
    int* cnt = (int*)(ws + W_CNT);
    float4* cpk = (float4*)(ws + W_CPK);
    int* inds_i = (int*)(ws + W_INDS);
    int* maskw = (int*)(ws + W_MASK);

    // K0: prep
    k0_prep<<<dim3((298988 + 255) / 256), dim3(256), 0, stream>>>(
        gh_w1, w1, w2, w3, gh_g1, gh_v1, g1, v1, g2, v2, ws);

    // K1: fused stage A (64-wide tiles)
    k1_stageA<<<dim3((NN + 63) / 64, BB), dim3(256), 0, stream>>>(
        seed_feat, ws + W_GH1T, gh_b1, ws + W_SGH, gh_m1, gh_be1, gh_w2, gh_b2,
        out + O_GRASP, out + O_OBJ, maskw);

    // K2: compaction (wave-aggregated atomics)
    k2_compact<<<dim3((NN + 255) / 256, BB), dim3(256), 0, stream>>>(seed_xyz, maskw, cnt, cpk);

    // K3: FPS (three self-selecting register-capacity variants; need = ceil(M/256))
    k3_fps<24><<<dim3(BB), dim3(256), 0, stream>>>(cpk, cnt, out + O_INDS, inds_i, -1, 24);
    k3_fps<40><<<dim3(BB), dim3(256), 0, stream>>>(cpk, cnt, out + O_INDS, inds_i, 24, 40);
    k3_fps<79><<<dim3(BB), dim3(256), 0, stream>>>(cpk, cnt, out + O_INDS, inds_i, 40, 79);

    // K4: gathers
    k4_gatherF<<<dim3(BB * CC * SS / 256), dim3(256), 0, stream>>>(seed_feat, inds_i, out + O_GFEAT);
    k4_gatherX<<<dim3(BB * SS / 256), dim3(256), 0, stream>>>(
        seed_xyz, inds_i, out + O_GRASP, out + O_GXYZ, out + O_FPG);

    // K5: stage C MLP (three conv1x1 layers)
    k5_gemm<<<dim3(4, 16, BB), dim3(256), 0, stream>>>(
        out + O_GFEAT, ws + W_W1T, b1, ws + W_SC1, m1, be1, ws + W_F1, 256, 256, 256, 1);
    k5_gemm<<<dim3(5, 16, BB), dim3(256), 0, stream>>>(
        ws + W_F1, ws + W_W2T, b2, ws + W_SC2, m2, be2, ws + W_F2, 300, 320, 256, 1);
    k5_gemm<<<dim3(5, 16, BB), dim3(256), 0, stream>>>(
        ws + W_F2, ws + W_W3T, b3, b3, b3, b3, ws + W_F3, 300, 320, 300, 0);

    // K7: view_score transpose (before K6, which reads it)
    k7_transpose<<<dim3(5, 16, BB), dim3(256), 0, stream>>>(ws + W_F3, out + O_VIEW);

    // K6: view argmax + rotations (reads transposed view_score)
    k6_view<<<dim3(BB * SS / 256), dim3(256), 0, stream>>>(
        out + O_VIEW, ws + W_TMPL, out + O_TVI, out + O_TVS, out + O_VPX, out + O_VPR);
}